// Round 4
// baseline (197.434 us; speedup 1.0000x reference)
//
#include <hip/hip_runtime.h>
#include <math.h>

// Problem constants: B=2, C=256, DM=512, H=8, D=64, SPARSE_K=64
typedef __bf16 bf16;
typedef __attribute__((ext_vector_type(4))) __bf16 bf16x4;
typedef __attribute__((ext_vector_type(8))) __bf16 bf16x8;
typedef __attribute__((ext_vector_type(4))) float floatx4;

// ---------------------------------------------------------------------------
// Branchless exact-enough gelu via Abramowitz-Stegun 7.1.26 erf
// (abs err <= 1.5e-7 for ALL t, no divergence). Replaces the Taylor+erff
// fallback: the old branch was per-element rare but per-WAVE common (128
// elements/call), so most waves executed the ~40-instr libm erff body on
// top of the Taylor path. This version: ~14 ops, 1 exp, 1 rcp, 0 branches.
// ---------------------------------------------------------------------------
__device__ __forceinline__ float gelu_exact(float x) {
    float t = x * 0.70710678118654752440f;
    float a = fabsf(t);
    float k = __frcp_rn(fmaf(0.3275911f, a, 1.0f));
    float p = fmaf(k, 1.061405429f, -1.453152027f);
    p = fmaf(k, p, 1.421413741f);
    p = fmaf(k, p, -0.284496736f);
    p = fmaf(k, p, 0.254829592f);
    p = p * k;
    float ex = __expf(-t * t);
    float e = 1.0f - p * ex;          // erf(|t|)
    e = copysignf(e, t);
    return 0.5f * x * (1.0f + e);
}

__device__ __forceinline__ void split3(float a, bf16& h, bf16& m, bf16& l) {
    h = (bf16)a;  float r1 = a - (float)h;
    m = (bf16)r1; float r2 = r1 - (float)m;
    l = (bf16)r2;
}

// ---------------------------------------------------------------------------
// Triple-split into MFMA frag-major order for [512][512] matrices; 5 matrices
// batched via blockIdx.z. (row,k) -> ((rt*16+ks)*64 + q4*16 + rm)*8 + u.
// ---------------------------------------------------------------------------
struct SplitArgs {
    const float* src[5];
    bf16* h[5]; bf16* m[5]; bf16* l[5];
};

__global__ __launch_bounds__(256) void split3_512_kernel(SplitArgs S) {
    int z = blockIdx.z;
    const float* src = S.src[z];
    bf16* dh = S.h[z]; bf16* dm = S.m[z]; bf16* dl = S.l[z];
    int t = blockIdx.x * 256 + threadIdx.x;
    int row = t >> 7, kq = (t & 127) * 4;
    int rt = row >> 4, rm = row & 15;
    int ks = kq >> 5, q4 = (kq >> 3) & 3, u0 = kq & 7;
    int dst = ((rt * 16 + ks) * 64 + q4 * 16 + rm) * 8 + u0;
    float4 vv = *(const float4*)&src[row * 512 + kq];
    float a4[4] = {vv.x, vv.y, vv.z, vv.w};
    bf16x4 h, m, l;
    #pragma unroll
    for (int u = 0; u < 4; u++) {
        bf16 hh, mm, ll;
        split3(a4[u], hh, mm, ll);
        h[u] = hh; m[u] = mm; l[u] = ll;
    }
    *(bf16x4*)&dh[dst] = h;
    *(bf16x4*)&dm[dst] = m;
    *(bf16x4*)&dl[dst] = l;
}

// ---------------------------------------------------------------------------
// C = A @ W^T + bias via triple-split bf16 MFMA. One wave per block computing
// a 16(m) x 16(n) tile; grid (32 nx, 32 ny, nz). 6 MFMAs per k-step split
// into TWO independent 3-chains. mode 0: fp32 [m*512+n]; mode 1: heads fp32
// (b,h,c,d); mode 2: K written directly as frag-major split triple.
// ---------------------------------------------------------------------------
struct MM2Args {
    const bf16 *Ah, *Am, *Al;
    const bf16 *Wh[3], *Wm[3], *Wl[3];
    const float* bias[3];
    float* outf[3];
    bf16 *kh, *km, *kl;
    int mode[3];
};

__global__ __launch_bounds__(64) void mm_mfma_kernel(MM2Args A) {
    const int z = blockIdx.z;
    const bf16* Wh = A.Wh[z]; const bf16* Wm = A.Wm[z]; const bf16* Wl = A.Wl[z];
    const float* bias = A.bias[z];
    const int lane = threadIdx.x;
    const int m16 = lane & 15, q4 = lane >> 4;
    const int mt = blockIdx.y, bx = blockIdx.x;

    floatx4 acc0, acc1;
    {
        float bv = bias[bx * 16 + m16];
        acc0[0] = bv; acc0[1] = bv; acc0[2] = bv; acc0[3] = bv;
        acc1[0] = 0.f; acc1[1] = 0.f; acc1[2] = 0.f; acc1[3] = 0.f;
    }

    #pragma unroll 4
    for (int ks = 0; ks < 16; ks++) {
        int sa = ((mt * 16 + ks) * 64 + lane) * 8;
        bf16x8 ah = *(const bf16x8*)&A.Ah[sa];
        bf16x8 am = *(const bf16x8*)&A.Am[sa];
        bf16x8 al = *(const bf16x8*)&A.Al[sa];
        int sw = ((bx * 16 + ks) * 64 + lane) * 8;
        bf16x8 wh = *(const bf16x8*)&Wh[sw];
        bf16x8 wm = *(const bf16x8*)&Wm[sw];
        bf16x8 wl = *(const bf16x8*)&Wl[sw];
        acc0 = __builtin_amdgcn_mfma_f32_16x16x32_bf16(ah, wh, acc0, 0, 0, 0);
        acc1 = __builtin_amdgcn_mfma_f32_16x16x32_bf16(ah, wm, acc1, 0, 0, 0);
        acc0 = __builtin_amdgcn_mfma_f32_16x16x32_bf16(am, wh, acc0, 0, 0, 0);
        acc1 = __builtin_amdgcn_mfma_f32_16x16x32_bf16(ah, wl, acc1, 0, 0, 0);
        acc0 = __builtin_amdgcn_mfma_f32_16x16x32_bf16(al, wh, acc0, 0, 0, 0);
        acc1 = __builtin_amdgcn_mfma_f32_16x16x32_bf16(am, wm, acc1, 0, 0, 0);
    }
    floatx4 acc = acc0 + acc1;

    const int mode = A.mode[z];
    const int n = bx * 16 + m16;
    #pragma unroll
    for (int r = 0; r < 4; r++) {
        int m = mt * 16 + q4 * 4 + r;
        float val = acc[r];
        if (mode == 0) {
            A.outf[z][m * 512 + n] = val;
        } else if (mode == 1) {
            A.outf[z][(((m >> 8) * 8 + (n >> 6)) * 256 + (m & 255)) * 64 + (n & 63)] = val;
        } else {
            int krow = ((m >> 8) * 8 + (n >> 6)) * 256 + (m & 255);
            int d = n & 63;
            int dst = (((krow >> 4) * 2 + (d >> 5)) * 64 + ((d >> 3) & 3) * 16 + (krow & 15)) * 8 + (d & 7);
            bf16 h, mm, l;
            split3(val, h, mm, l);
            A.kh[dst] = h; A.km[dst] = mm; A.kl[dst] = l;
        }
    }
}

// ---------------------------------------------------------------------------
// Fused per-(bh, i-pair) — R0-verbatim structure (fastest measured: 90.4us):
// res^T[f,j] = qpb_i[f] + sum_e A_i[f,e]*K[j,e], A_i in registers per wave,
// NI=2 (K frags shared across 2 queries), 12-MFMA chain (unroll 2), dual
// bitonic top-64, softmax, attn@V, split-triple output. ONLY change vs R0:
// gelu_exact is now the branchless A&S erf (no per-wave erff divergence).
// Occupancy experiments (R2/R3) proved 3 waves/SIMD is the no-spill
// equilibrium -> (256,3) retained.
// ---------------------------------------------------------------------------
__global__ __launch_bounds__(256, 3) void fused_mfma_attn_kernel(
    const float* __restrict__ q, const float* __restrict__ v,
    const bf16* __restrict__ khi, const bf16* __restrict__ kmid, const bf16* __restrict__ klo,
    const float* __restrict__ w1, const float* __restrict__ b1,
    const float* __restrict__ w2, const float* __restrict__ b2,
    bf16* __restrict__ oh, bf16* __restrict__ om, bf16* __restrict__ ol)
{
    const int i2 = blockIdx.x;     // query pair: i = 2*i2 + i01
    const int bh = blockIdx.y;
    const int t  = threadIdx.x;
    const int lane = t & 63, w = t >> 6;
    const int m16 = lane & 15, q4 = lane >> 4;

    __shared__ float part[2][4][256];   // per-wave f-partials of scores
    __shared__ float sc[2][256];        // softmax probabilities
    __shared__ float qpb_s[2][64];
    __shared__ float sbuf[2][256];      // bitonic cross-wave exchange
    __shared__ float red[2][4][64];
    __shared__ float red2[2][4];
    __shared__ float thr_s[2], smax_s[2];

    const int f = w * 16 + m16;         // this lane's f (A-operand M index)
    const float* w1row = w1 + f * 192;

    // ---- build A_i fragments in registers + qpb
    bf16x8 Ah[2][2], Am[2][2], Al[2][2];
    #pragma unroll
    for (int i01 = 0; i01 < 2; i01++) {
        const float* qrow = q + (bh * 256 + i2 * 2 + i01) * 64;
        float qa = 0.f;
        #pragma unroll
        for (int ks = 0; ks < 2; ks++) {
            int e0 = ks * 32 + q4 * 8;
            #pragma unroll
            for (int u = 0; u < 2; u++) {
                int e = e0 + u * 4;
                float4 wa = *(const float4*)&w1row[e];
                float4 wb = *(const float4*)&w1row[64 + e];
                float4 wc = *(const float4*)&w1row[128 + e];
                float4 qv = *(const float4*)&qrow[e];
                qa += wa.x * qv.x + wa.y * qv.y + wa.z * qv.z + wa.w * qv.w;
                float av[4];
                av[0] = fmaf(wc.x, qv.x, wb.x);
                av[1] = fmaf(wc.y, qv.y, wb.y);
                av[2] = fmaf(wc.z, qv.z, wb.z);
                av[3] = fmaf(wc.w, qv.w, wb.w);
                #pragma unroll
                for (int uu = 0; uu < 4; uu++) {
                    bf16 h, m, l;
                    split3(av[uu], h, m, l);
                    Ah[i01][ks][u * 4 + uu] = h;
                    Am[i01][ks][u * 4 + uu] = m;
                    Al[i01][ks][u * 4 + uu] = l;
                }
            }
        }
        qa += __shfl_xor(qa, 16);
        qa += __shfl_xor(qa, 32);
        if (lane < 16) qpb_s[i01][w * 16 + lane] = qa + b1[w * 16 + lane];
    }
    __syncthreads();

    floatx4 qpbr[2];
    qpbr[0] = *(const floatx4*)&qpb_s[0][w * 16 + q4 * 4];
    qpbr[1] = *(const floatx4*)&qpb_s[1][w * 16 + q4 * 4];
    const float4 w2f = *(const float4*)&w2[w * 16 + q4 * 4];
    const float b2v = b2[0];

    // ---- main loop over j-tiles: MFMA + immediate epilogue (no barriers)
    #pragma unroll 2
    for (int jt = 0; jt < 16; jt++) {
        int base = ((bh * 16 + jt) * 2 * 64 + lane) * 8;
        bf16x8 Kh0 = *(const bf16x8*)&khi [base];
        bf16x8 Km0 = *(const bf16x8*)&kmid[base];
        bf16x8 Kl0 = *(const bf16x8*)&klo [base];
        bf16x8 Kh1 = *(const bf16x8*)&khi [base + 512];
        bf16x8 Km1 = *(const bf16x8*)&kmid[base + 512];
        bf16x8 Kl1 = *(const bf16x8*)&klo [base + 512];
        #pragma unroll
        for (int i01 = 0; i01 < 2; i01++) {
            floatx4 a = qpbr[i01];
            a = __builtin_amdgcn_mfma_f32_16x16x32_bf16(Ah[i01][0], Kh0, a, 0, 0, 0);
            a = __builtin_amdgcn_mfma_f32_16x16x32_bf16(Ah[i01][0], Km0, a, 0, 0, 0);
            a = __builtin_amdgcn_mfma_f32_16x16x32_bf16(Am[i01][0], Kh0, a, 0, 0, 0);
            a = __builtin_amdgcn_mfma_f32_16x16x32_bf16(Ah[i01][0], Kl0, a, 0, 0, 0);
            a = __builtin_amdgcn_mfma_f32_16x16x32_bf16(Al[i01][0], Kh0, a, 0, 0, 0);
            a = __builtin_amdgcn_mfma_f32_16x16x32_bf16(Am[i01][0], Km0, a, 0, 0, 0);
            a = __builtin_amdgcn_mfma_f32_16x16x32_bf16(Ah[i01][1], Kh1, a, 0, 0, 0);
            a = __builtin_amdgcn_mfma_f32_16x16x32_bf16(Ah[i01][1], Km1, a, 0, 0, 0);
            a = __builtin_amdgcn_mfma_f32_16x16x32_bf16(Am[i01][1], Kh1, a, 0, 0, 0);
            a = __builtin_amdgcn_mfma_f32_16x16x32_bf16(Ah[i01][1], Kl1, a, 0, 0, 0);
            a = __builtin_amdgcn_mfma_f32_16x16x32_bf16(Al[i01][1], Kh1, a, 0, 0, 0);
            a = __builtin_amdgcn_mfma_f32_16x16x32_bf16(Am[i01][1], Km1, a, 0, 0, 0);
            // epilogue: rows of a = 4 f's (q4*4+r), col = j = jt*16+m16
            float s = 0.f;
            s = fmaf(w2f.x, gelu_exact(a[0]), s);
            s = fmaf(w2f.y, gelu_exact(a[1]), s);
            s = fmaf(w2f.z, gelu_exact(a[2]), s);
            s = fmaf(w2f.w, gelu_exact(a[3]), s);
            s += __shfl_xor(s, 16);
            s += __shfl_xor(s, 32);
            if (lane < 16) part[i01][w][jt * 16 + lane] = s;
        }
    }
    __syncthreads();

    // ---- scores
    float score[2];
    #pragma unroll
    for (int i01 = 0; i01 < 2; i01++) {
        score[i01] = (((part[i01][0][t] + part[i01][1][t]) +
                       (part[i01][2][t] + part[i01][3][t])) + b2v) * 0.125f;
    }

    // ---- dual lockstep 256-wide bitonic sort; sorted[192] = 64th largest.
    float sv0 = score[0], sv1 = score[1];
    #pragma unroll
    for (int k = 2; k <= 256; k <<= 1) {
        #pragma unroll
        for (int j = k >> 1; j >= 1; j >>= 1) {
            float pv0, pv1;
            if (j >= 64) {
                sbuf[0][t] = sv0; sbuf[1][t] = sv1;
                __syncthreads();
                pv0 = sbuf[0][t ^ j]; pv1 = sbuf[1][t ^ j];
                __syncthreads();
            } else {
                pv0 = __shfl_xor(sv0, j);
                pv1 = __shfl_xor(sv1, j);
            }
            bool keepMin = (((t & j) == 0) == ((t & k) == 0));
            sv0 = keepMin ? fminf(sv0, pv0) : fmaxf(sv0, pv0);
            sv1 = keepMin ? fminf(sv1, pv1) : fmaxf(sv1, pv1);
        }
    }
    if (t == 192) { thr_s[0] = sv0; thr_s[1] = sv1; }
    if (t == 255) { smax_s[0] = sv0; smax_s[1] = sv1; }
    __syncthreads();

    // ---- softmax numerator + denominator
    float p0 = (score[0] >= thr_s[0]) ? __expf(score[0] - smax_s[0]) : 0.0f;
    float p1 = (score[1] >= thr_s[1]) ? __expf(score[1] - smax_s[1]) : 0.0f;
    sc[0][t] = p0; sc[1][t] = p1;
    float ps0 = p0, ps1 = p1;
    #pragma unroll
    for (int mask = 1; mask < 64; mask <<= 1) {
        ps0 += __shfl_xor(ps0, mask);
        ps1 += __shfl_xor(ps1, mask);
    }
    if (lane == 0) { red2[0][w] = ps0; red2[1][w] = ps1; }
    __syncthreads();
    const float inv0 = 1.0f / ((red2[0][0] + red2[0][1]) + (red2[0][2] + red2[0][3]));
    const float inv1 = 1.0f / ((red2[1][0] + red2[1][1]) + (red2[1][2] + red2[1][3]));

    // ---- attn @ V (v loads shared between the two i's)
    const int d = t & 63, g = t >> 6;
    const float* vb = v + bh * 256 * 64;
    float a0 = 0.f, a1 = 0.f;
    for (int j4 = 0; j4 < 16; j4++) {
        int jj = g * 64 + j4 * 4;
        float4 p40 = *(const float4*)&sc[0][jj];
        float4 p41 = *(const float4*)&sc[1][jj];
        float v0 = vb[(jj + 0) * 64 + d];
        float v1 = vb[(jj + 1) * 64 + d];
        float v2 = vb[(jj + 2) * 64 + d];
        float v3 = vb[(jj + 3) * 64 + d];
        a0 = fmaf(p40.x, v0, a0); a1 = fmaf(p41.x, v0, a1);
        a0 = fmaf(p40.y, v1, a0); a1 = fmaf(p41.y, v1, a1);
        a0 = fmaf(p40.z, v2, a0); a1 = fmaf(p41.z, v2, a1);
        a0 = fmaf(p40.w, v3, a0); a1 = fmaf(p41.w, v3, a1);
    }
    red[0][g][d] = a0; red[1][g][d] = a1;
    __syncthreads();

    // ---- output: (B,H,C,D)->(B,C,DM) row, written as split frag-major triple
    if (t < 128) {
        int i01 = t >> 6, dd = t & 63;
        float o = ((red[i01][0][dd] + red[i01][1][dd]) +
                   (red[i01][2][dd] + red[i01][3][dd])) * (i01 ? inv1 : inv0);
        int b = bh >> 3, h = bh & 7;
        int row = b * 256 + i2 * 2 + i01;
        int n = h * 64 + dd;
        int dst = (((row >> 4) * 16 + (n >> 5)) * 64 + ((n >> 3) & 3) * 16 + (row & 15)) * 8 + (n & 7);
        bf16 hh, mm, ll;
        split3(o, hh, mm, ll);
        oh[dst] = hh; om[dst] = mm; ol[dst] = ll;
    }
}

// ---------------------------------------------------------------------------
extern "C" void kernel_launch(void* const* d_in, const int* in_sizes, int n_in,
                              void* d_out, int out_size, void* d_ws, size_t ws_size,
                              hipStream_t stream) {
    const float* x  = (const float*)d_in[0];
    const float* Wq = (const float*)d_in[1];
    const float* bq = (const float*)d_in[2];
    const float* Wk = (const float*)d_in[3];
    const float* bk = (const float*)d_in[4];
    const float* Wv = (const float*)d_in[5];
    const float* bv = (const float*)d_in[6];
    const float* w1 = (const float*)d_in[7];
    const float* b1 = (const float*)d_in[8];
    const float* w2 = (const float*)d_in[9];
    const float* b2 = (const float*)d_in[10];
    const float* Wo = (const float*)d_in[11];
    const float* bo = (const float*)d_in[12];
    float* out = (float*)d_out;

    const int NE = 262144;   // 512*512
    float* qb  = (float*)d_ws;          // q (b,h,c,d) fp32
    float* vb  = qb + NE;               // v (b,h,c,d) fp32
    bf16* base = (bf16*)(vb + NE);
    bf16* khi  = base;            bf16* kmid = khi + NE;    bf16* klo = kmid + NE;
    bf16* xs   = klo + NE;        // hi/mid/lo triples follow
    bf16* wqs  = xs  + 3 * NE;
    bf16* wks  = wqs + 3 * NE;
    bf16* wvs  = wks + 3 * NE;
    bf16* wos  = wvs + 3 * NE;
    bf16* oas  = wos + 3 * NE;

    // 1) split x, Wq, Wk, Wv, Wo into frag-major bf16 triples
    {
        SplitArgs S;
        const float* srcs[5] = {x, Wq, Wk, Wv, Wo};
        bf16* dsts[5] = {xs, wqs, wks, wvs, wos};
        for (int z = 0; z < 5; z++) {
            S.src[z] = srcs[z];
            S.h[z] = dsts[z]; S.m[z] = dsts[z] + NE; S.l[z] = dsts[z] + 2 * NE;
        }
        split3_512_kernel<<<dim3(256, 1, 5), 256, 0, stream>>>(S);
    }
    // 2) QKV projections; K written directly as split frag-major triple
    {
        MM2Args M;
        M.Ah = xs; M.Am = xs + NE; M.Al = xs + 2 * NE;
        M.Wh[0] = wqs; M.Wm[0] = wqs + NE; M.Wl[0] = wqs + 2 * NE;
        M.Wh[1] = wks; M.Wm[1] = wks + NE; M.Wl[1] = wks + 2 * NE;
        M.Wh[2] = wvs; M.Wm[2] = wvs + NE; M.Wl[2] = wvs + 2 * NE;
        M.bias[0] = bq; M.bias[1] = bk; M.bias[2] = bv;
        M.outf[0] = qb; M.outf[1] = nullptr; M.outf[2] = vb;
        M.kh = khi; M.km = kmid; M.kl = klo;
        M.mode[0] = 1; M.mode[1] = 2; M.mode[2] = 1;
        mm_mfma_kernel<<<dim3(32, 32, 3), 64, 0, stream>>>(M);
    }
    // 3) fused second-order scores + top-64 + softmax + attn@V (+ split out)
    fused_mfma_attn_kernel<<<dim3(128, 16), 256, 0, stream>>>(
        qb, vb, khi, kmid, klo, w1, b1, w2, b2,
        oas, oas + NE, oas + 2 * NE);
    // 4) output projection
    {
        MM2Args M;
        M.Ah = oas; M.Am = oas + NE; M.Al = oas + 2 * NE;
        M.Wh[0] = wos; M.Wm[0] = wos + NE; M.Wl[0] = wos + 2 * NE;
        M.Wh[1] = wos; M.Wm[1] = wos; M.Wl[1] = wos;
        M.Wh[2] = wos; M.Wm[2] = wos; M.Wl[2] = wos;
        M.bias[0] = bo; M.bias[1] = bo; M.bias[2] = bo;
        M.outf[0] = out; M.outf[1] = out; M.outf[2] = out;
        M.kh = khi; M.km = kmid; M.kl = klo;
        M.mode[0] = 0; M.mode[1] = 0; M.mode[2] = 0;
        mm_mfma_kernel<<<dim3(32, 32, 1), 64, 0, stream>>>(M);
    }
}

// Round 5
// 177.165 us; speedup vs baseline: 1.1144x; 1.1144x over previous
//
#include <hip/hip_runtime.h>
#include <math.h>

// Problem constants: B=2, C=256, DM=512, H=8, D=64, SPARSE_K=64
typedef _Float16 fp16;
typedef __attribute__((ext_vector_type(4))) _Float16 f16x4;
typedef __attribute__((ext_vector_type(8))) _Float16 f16x8;
typedef __attribute__((ext_vector_type(4))) float floatx4;

// ---------------------------------------------------------------------------
// R0-proven gelu: 6-term Taylor erf on |t|<=0.5 (abs err <= 1.5e-8), erff
// fallback for rare outliers. (R4 measured the branchless exp-based variant
// at +21% kernel time — the branch is cheap in practice; keep this one.)
// ---------------------------------------------------------------------------
__device__ __forceinline__ float gelu_exact(float x) {
    float tt = x * 0.70710678118654752440f;
    float e;
    if (__builtin_expect(fabsf(tt) > 0.5f, 0)) {
        e = erff(tt);
    } else {
        float s = tt * tt;
        e = tt * fmaf(s, fmaf(s, fmaf(s, fmaf(s, fmaf(s,
                -8.548327023450852e-4f, 5.223977625442188e-3f),
                -2.6866170645131252e-2f), 0.11283791670955126f),
                -0.3761263890318375f), 1.1283791670955126f);
    }
    return 0.5f * x * (1.0f + e);
}

// ---------------------------------------------------------------------------
// fp16 DUAL split (R5): h = fp16(x) (11-bit mantissa), m = fp16(x - h).
// h+m covers ~22 mantissa bits; fp16*fp16 products are EXACT in the fp32
// MFMA accumulator (11+11 <= 24 bits), so keeping all 4 cross-products
// (hh,hm,mh,mm) gives error ~2^-22 rel — better than the previous 6-term
// bf16 triple-split at 2/3 the MFMA count (4 vs 6 per fp32 product).
// ---------------------------------------------------------------------------
__device__ __forceinline__ void split2(float a, fp16& h, fp16& m) {
    h = (fp16)a;
    m = (fp16)(a - (float)h);
}

// ---------------------------------------------------------------------------
// Dual-split into MFMA frag-major order for [512][512] matrices; 5 matrices
// batched via blockIdx.z. (row,k) -> ((rt*16+ks)*64 + q4*16 + rm)*8 + u.
// ---------------------------------------------------------------------------
struct SplitArgs {
    const float* src[5];
    fp16* h[5]; fp16* m[5];
};

__global__ __launch_bounds__(256) void split2_512_kernel(SplitArgs S) {
    int z = blockIdx.z;
    const float* src = S.src[z];
    fp16* dh = S.h[z]; fp16* dm = S.m[z];
    int t = blockIdx.x * 256 + threadIdx.x;
    int row = t >> 7, kq = (t & 127) * 4;
    int rt = row >> 4, rm = row & 15;
    int ks = kq >> 5, q4 = (kq >> 3) & 3, u0 = kq & 7;
    int dst = ((rt * 16 + ks) * 64 + q4 * 16 + rm) * 8 + u0;
    float4 vv = *(const float4*)&src[row * 512 + kq];
    float a4[4] = {vv.x, vv.y, vv.z, vv.w};
    f16x4 h, m;
    #pragma unroll
    for (int u = 0; u < 4; u++) {
        fp16 hh, mm;
        split2(a4[u], hh, mm);
        h[u] = hh; m[u] = mm;
    }
    *(f16x4*)&dh[dst] = h;
    *(f16x4*)&dm[dst] = m;
}

// ---------------------------------------------------------------------------
// C = A @ W^T + bias via dual-split fp16 MFMA. One wave per block computing
// a 16(m) x 16(n) tile; grid (32 nx, 32 ny, nz). 4 MFMAs per k-step in TWO
// independent 2-chains. mode 0: fp32 [m*512+n]; mode 1: heads fp32
// (b,h,c,d); mode 2: K written directly as frag-major dual-split.
// ---------------------------------------------------------------------------
struct MM2Args {
    const fp16 *Ah, *Am;
    const fp16 *Wh[3], *Wm[3];
    const float* bias[3];
    float* outf[3];
    fp16 *kh, *km;
    int mode[3];
};

__global__ __launch_bounds__(64) void mm_mfma_kernel(MM2Args A) {
    const int z = blockIdx.z;
    const fp16* Wh = A.Wh[z]; const fp16* Wm = A.Wm[z];
    const float* bias = A.bias[z];
    const int lane = threadIdx.x;
    const int m16 = lane & 15, q4 = lane >> 4;
    const int mt = blockIdx.y, bx = blockIdx.x;

    floatx4 acc0, acc1;
    {
        float bv = bias[bx * 16 + m16];
        acc0[0] = bv; acc0[1] = bv; acc0[2] = bv; acc0[3] = bv;
        acc1[0] = 0.f; acc1[1] = 0.f; acc1[2] = 0.f; acc1[3] = 0.f;
    }

    #pragma unroll 4
    for (int ks = 0; ks < 16; ks++) {
        int sa = ((mt * 16 + ks) * 64 + lane) * 8;
        f16x8 ah = *(const f16x8*)&A.Ah[sa];
        f16x8 am = *(const f16x8*)&A.Am[sa];
        int sw = ((bx * 16 + ks) * 64 + lane) * 8;
        f16x8 wh = *(const f16x8*)&Wh[sw];
        f16x8 wm = *(const f16x8*)&Wm[sw];
        acc0 = __builtin_amdgcn_mfma_f32_16x16x32_f16(ah, wh, acc0, 0, 0, 0);
        acc1 = __builtin_amdgcn_mfma_f32_16x16x32_f16(ah, wm, acc1, 0, 0, 0);
        acc0 = __builtin_amdgcn_mfma_f32_16x16x32_f16(am, wh, acc0, 0, 0, 0);
        acc1 = __builtin_amdgcn_mfma_f32_16x16x32_f16(am, wm, acc1, 0, 0, 0);
    }
    floatx4 acc = acc0 + acc1;

    const int mode = A.mode[z];
    const int n = bx * 16 + m16;
    #pragma unroll
    for (int r = 0; r < 4; r++) {
        int m = mt * 16 + q4 * 4 + r;
        float val = acc[r];
        if (mode == 0) {
            A.outf[z][m * 512 + n] = val;
        } else if (mode == 1) {
            A.outf[z][(((m >> 8) * 8 + (n >> 6)) * 256 + (m & 255)) * 64 + (n & 63)] = val;
        } else {
            int krow = ((m >> 8) * 8 + (n >> 6)) * 256 + (m & 255);
            int d = n & 63;
            int dst = (((krow >> 4) * 2 + (d >> 5)) * 64 + ((d >> 3) & 3) * 16 + (krow & 15)) * 8 + (d & 7);
            fp16 h, mm;
            split2(val, h, mm);
            A.kh[dst] = h; A.km[dst] = mm;
        }
    }
}

// ---------------------------------------------------------------------------
// Fused per-(bh, i-pair): R0 structure with fp16 dual-split MFMA (R5).
// 8 MFMAs per (jt,i01) instead of 12 (two independent 4-chains), 4 K-load
// streams instead of 6, A-frags 32 VGPR instead of 48, K frags 16 vs 24.
// The ~24-reg relief gives __launch_bounds__(256,4) a real chance to seat a
// 4th wave/SIMD (R3 proved the hint is harmless when infeasible).
// ---------------------------------------------------------------------------
__global__ __launch_bounds__(256, 4) void fused_mfma_attn_kernel(
    const float* __restrict__ q, const float* __restrict__ v,
    const fp16* __restrict__ khi, const fp16* __restrict__ kmid,
    const float* __restrict__ w1, const float* __restrict__ b1,
    const float* __restrict__ w2, const float* __restrict__ b2,
    fp16* __restrict__ oh, fp16* __restrict__ om)
{
    const int i2 = blockIdx.x;     // query pair: i = 2*i2 + i01
    const int bh = blockIdx.y;
    const int t  = threadIdx.x;
    const int lane = t & 63, w = t >> 6;
    const int m16 = lane & 15, q4 = lane >> 4;

    __shared__ float part[2][4][256];   // per-wave f-partials of scores
    __shared__ float sc[2][256];        // softmax probabilities
    __shared__ float qpb_s[2][64];
    __shared__ float sbuf[2][256];      // bitonic cross-wave exchange
    __shared__ float red[2][4][64];
    __shared__ float red2[2][4];
    __shared__ float thr_s[2], smax_s[2];

    const int f = w * 16 + m16;         // this lane's f (A-operand M index)
    const float* w1row = w1 + f * 192;

    // ---- build A_i fragments in registers + qpb
    f16x8 Ah[2][2], Am[2][2];
    #pragma unroll
    for (int i01 = 0; i01 < 2; i01++) {
        const float* qrow = q + (bh * 256 + i2 * 2 + i01) * 64;
        float qa = 0.f;
        #pragma unroll
        for (int ks = 0; ks < 2; ks++) {
            int e0 = ks * 32 + q4 * 8;
            #pragma unroll
            for (int u = 0; u < 2; u++) {
                int e = e0 + u * 4;
                float4 wa = *(const float4*)&w1row[e];
                float4 wb = *(const float4*)&w1row[64 + e];
                float4 wc = *(const float4*)&w1row[128 + e];
                float4 qv = *(const float4*)&qrow[e];
                qa += wa.x * qv.x + wa.y * qv.y + wa.z * qv.z + wa.w * qv.w;
                float av[4];
                av[0] = fmaf(wc.x, qv.x, wb.x);
                av[1] = fmaf(wc.y, qv.y, wb.y);
                av[2] = fmaf(wc.z, qv.z, wb.z);
                av[3] = fmaf(wc.w, qv.w, wb.w);
                #pragma unroll
                for (int uu = 0; uu < 4; uu++) {
                    fp16 h, m;
                    split2(av[uu], h, m);
                    Ah[i01][ks][u * 4 + uu] = h;
                    Am[i01][ks][u * 4 + uu] = m;
                }
            }
        }
        qa += __shfl_xor(qa, 16);
        qa += __shfl_xor(qa, 32);
        if (lane < 16) qpb_s[i01][w * 16 + lane] = qa + b1[w * 16 + lane];
    }
    __syncthreads();

    floatx4 qpbr[2];
    qpbr[0] = *(const floatx4*)&qpb_s[0][w * 16 + q4 * 4];
    qpbr[1] = *(const floatx4*)&qpb_s[1][w * 16 + q4 * 4];
    const float4 w2f = *(const float4*)&w2[w * 16 + q4 * 4];
    const float b2v = b2[0];

    // ---- main loop over j-tiles: MFMA (two independent 4-chains) + epilogue
    #pragma unroll 2
    for (int jt = 0; jt < 16; jt++) {
        int base = ((bh * 16 + jt) * 2 * 64 + lane) * 8;
        f16x8 Kh0 = *(const f16x8*)&khi [base];
        f16x8 Km0 = *(const f16x8*)&kmid[base];
        f16x8 Kh1 = *(const f16x8*)&khi [base + 512];
        f16x8 Km1 = *(const f16x8*)&kmid[base + 512];
        #pragma unroll
        for (int i01 = 0; i01 < 2; i01++) {
            floatx4 a = qpbr[i01];
            floatx4 a2;
            a2[0] = 0.f; a2[1] = 0.f; a2[2] = 0.f; a2[3] = 0.f;
            a  = __builtin_amdgcn_mfma_f32_16x16x32_f16(Ah[i01][0], Kh0, a,  0, 0, 0);
            a2 = __builtin_amdgcn_mfma_f32_16x16x32_f16(Ah[i01][0], Km0, a2, 0, 0, 0);
            a  = __builtin_amdgcn_mfma_f32_16x16x32_f16(Am[i01][0], Kh0, a,  0, 0, 0);
            a2 = __builtin_amdgcn_mfma_f32_16x16x32_f16(Am[i01][0], Km0, a2, 0, 0, 0);
            a  = __builtin_amdgcn_mfma_f32_16x16x32_f16(Ah[i01][1], Kh1, a,  0, 0, 0);
            a2 = __builtin_amdgcn_mfma_f32_16x16x32_f16(Ah[i01][1], Km1, a2, 0, 0, 0);
            a  = __builtin_amdgcn_mfma_f32_16x16x32_f16(Am[i01][1], Kh1, a,  0, 0, 0);
            a2 = __builtin_amdgcn_mfma_f32_16x16x32_f16(Am[i01][1], Km1, a2, 0, 0, 0);
            a = a + a2;
            // epilogue: rows of a = 4 f's (q4*4+r), col = j = jt*16+m16
            float s = 0.f;
            s = fmaf(w2f.x, gelu_exact(a[0]), s);
            s = fmaf(w2f.y, gelu_exact(a[1]), s);
            s = fmaf(w2f.z, gelu_exact(a[2]), s);
            s = fmaf(w2f.w, gelu_exact(a[3]), s);
            s += __shfl_xor(s, 16);
            s += __shfl_xor(s, 32);
            if (lane < 16) part[i01][w][jt * 16 + lane] = s;
        }
    }
    __syncthreads();

    // ---- scores
    float score[2];
    #pragma unroll
    for (int i01 = 0; i01 < 2; i01++) {
        score[i01] = (((part[i01][0][t] + part[i01][1][t]) +
                       (part[i01][2][t] + part[i01][3][t])) + b2v) * 0.125f;
    }

    // ---- dual lockstep 256-wide bitonic sort; sorted[192] = 64th largest.
    float sv0 = score[0], sv1 = score[1];
    #pragma unroll
    for (int k = 2; k <= 256; k <<= 1) {
        #pragma unroll
        for (int j = k >> 1; j >= 1; j >>= 1) {
            float pv0, pv1;
            if (j >= 64) {
                sbuf[0][t] = sv0; sbuf[1][t] = sv1;
                __syncthreads();
                pv0 = sbuf[0][t ^ j]; pv1 = sbuf[1][t ^ j];
                __syncthreads();
            } else {
                pv0 = __shfl_xor(sv0, j);
                pv1 = __shfl_xor(sv1, j);
            }
            bool keepMin = (((t & j) == 0) == ((t & k) == 0));
            sv0 = keepMin ? fminf(sv0, pv0) : fmaxf(sv0, pv0);
            sv1 = keepMin ? fminf(sv1, pv1) : fmaxf(sv1, pv1);
        }
    }
    if (t == 192) { thr_s[0] = sv0; thr_s[1] = sv1; }
    if (t == 255) { smax_s[0] = sv0; smax_s[1] = sv1; }
    __syncthreads();

    // ---- softmax numerator + denominator
    float p0 = (score[0] >= thr_s[0]) ? __expf(score[0] - smax_s[0]) : 0.0f;
    float p1 = (score[1] >= thr_s[1]) ? __expf(score[1] - smax_s[1]) : 0.0f;
    sc[0][t] = p0; sc[1][t] = p1;
    float ps0 = p0, ps1 = p1;
    #pragma unroll
    for (int mask = 1; mask < 64; mask <<= 1) {
        ps0 += __shfl_xor(ps0, mask);
        ps1 += __shfl_xor(ps1, mask);
    }
    if (lane == 0) { red2[0][w] = ps0; red2[1][w] = ps1; }
    __syncthreads();
    const float inv0 = 1.0f / ((red2[0][0] + red2[0][1]) + (red2[0][2] + red2[0][3]));
    const float inv1 = 1.0f / ((red2[1][0] + red2[1][1]) + (red2[1][2] + red2[1][3]));

    // ---- attn @ V (v loads shared between the two i's)
    const int d = t & 63, g = t >> 6;
    const float* vb = v + bh * 256 * 64;
    float a0 = 0.f, a1 = 0.f;
    for (int j4 = 0; j4 < 16; j4++) {
        int jj = g * 64 + j4 * 4;
        float4 p40 = *(const float4*)&sc[0][jj];
        float4 p41 = *(const float4*)&sc[1][jj];
        float v0 = vb[(jj + 0) * 64 + d];
        float v1 = vb[(jj + 1) * 64 + d];
        float v2 = vb[(jj + 2) * 64 + d];
        float v3 = vb[(jj + 3) * 64 + d];
        a0 = fmaf(p40.x, v0, a0); a1 = fmaf(p41.x, v0, a1);
        a0 = fmaf(p40.y, v1, a0); a1 = fmaf(p41.y, v1, a1);
        a0 = fmaf(p40.z, v2, a0); a1 = fmaf(p41.z, v2, a1);
        a0 = fmaf(p40.w, v3, a0); a1 = fmaf(p41.w, v3, a1);
    }
    red[0][g][d] = a0; red[1][g][d] = a1;
    __syncthreads();

    // ---- output: (B,H,C,D)->(B,C,DM) row, written as dual-split frag-major
    if (t < 128) {
        int i01 = t >> 6, dd = t & 63;
        float o = ((red[i01][0][dd] + red[i01][1][dd]) +
                   (red[i01][2][dd] + red[i01][3][dd])) * (i01 ? inv1 : inv0);
        int b = bh >> 3, h = bh & 7;
        int row = b * 256 + i2 * 2 + i01;
        int n = h * 64 + dd;
        int dst = (((row >> 4) * 16 + (n >> 5)) * 64 + ((n >> 3) & 3) * 16 + (row & 15)) * 8 + (n & 7);
        fp16 hh, mm;
        split2(o, hh, mm);
        oh[dst] = hh; om[dst] = mm;
    }
}

// ---------------------------------------------------------------------------
extern "C" void kernel_launch(void* const* d_in, const int* in_sizes, int n_in,
                              void* d_out, int out_size, void* d_ws, size_t ws_size,
                              hipStream_t stream) {
    const float* x  = (const float*)d_in[0];
    const float* Wq = (const float*)d_in[1];
    const float* bq = (const float*)d_in[2];
    const float* Wk = (const float*)d_in[3];
    const float* bk = (const float*)d_in[4];
    const float* Wv = (const float*)d_in[5];
    const float* bv = (const float*)d_in[6];
    const float* w1 = (const float*)d_in[7];
    const float* b1 = (const float*)d_in[8];
    const float* w2 = (const float*)d_in[9];
    const float* b2 = (const float*)d_in[10];
    const float* Wo = (const float*)d_in[11];
    const float* bo = (const float*)d_in[12];
    float* out = (float*)d_out;

    const int NE = 262144;   // 512*512
    float* qb  = (float*)d_ws;          // q (b,h,c,d) fp32
    float* vb  = qb + NE;               // v (b,h,c,d) fp32
    fp16* base = (fp16*)(vb + NE);
    fp16* khi  = base;            fp16* kmid = khi + NE;
    fp16* xs   = kmid + NE;       // hi/mid duals follow (2*NE each)
    fp16* wqs  = xs  + 2 * NE;
    fp16* wks  = wqs + 2 * NE;
    fp16* wvs  = wks + 2 * NE;
    fp16* wos  = wvs + 2 * NE;
    fp16* oas  = wos + 2 * NE;

    // 1) split x, Wq, Wk, Wv, Wo into frag-major fp16 duals
    {
        SplitArgs S;
        const float* srcs[5] = {x, Wq, Wk, Wv, Wo};
        fp16* dsts[5] = {xs, wqs, wks, wvs, wos};
        for (int z = 0; z < 5; z++) {
            S.src[z] = srcs[z];
            S.h[z] = dsts[z]; S.m[z] = dsts[z] + NE;
        }
        split2_512_kernel<<<dim3(256, 1, 5), 256, 0, stream>>>(S);
    }
    // 2) QKV projections; K written directly as dual-split frag-major
    {
        MM2Args M;
        M.Ah = xs; M.Am = xs + NE;
        M.Wh[0] = wqs; M.Wm[0] = wqs + NE;
        M.Wh[1] = wks; M.Wm[1] = wks + NE;
        M.Wh[2] = wvs; M.Wm[2] = wvs + NE;
        M.bias[0] = bq; M.bias[1] = bk; M.bias[2] = bv;
        M.outf[0] = qb; M.outf[1] = nullptr; M.outf[2] = vb;
        M.kh = khi; M.km = kmid;
        M.mode[0] = 1; M.mode[1] = 2; M.mode[2] = 1;
        mm_mfma_kernel<<<dim3(32, 32, 3), 64, 0, stream>>>(M);
    }
    // 3) fused second-order scores + top-64 + softmax + attn@V (+ dual out)
    fused_mfma_attn_kernel<<<dim3(128, 16), 256, 0, stream>>>(
        qb, vb, khi, kmid, w1, b1, w2, b2,
        oas, oas + NE);
    // 4) output projection
    {
        MM2Args M;
        M.Ah = oas; M.Am = oas + NE;
        M.Wh[0] = wos; M.Wm[0] = wos + NE;
        M.Wh[1] = wos; M.Wm[1] = wos;
        M.Wh[2] = wos; M.Wm[2] = wos;
        M.bias[0] = bo; M.bias[1] = bo; M.bias[2] = bo;
        M.outf[0] = out; M.outf[1] = out; M.outf[2] = out;
        M.kh = khi; M.km = kmid;
        M.mode[0] = 0; M.mode[1] = 0; M.mode[2] = 0;
        mm_mfma_kernel<<<dim3(32, 32, 1), 64, 0, stream>>>(M);
    }
}

// Round 6
// 174.937 us; speedup vs baseline: 1.1286x; 1.0127x over previous
//
#include <hip/hip_runtime.h>
#include <math.h>

// Problem constants: B=2, C=256, DM=512, H=8, D=64, SPARSE_K=64
typedef _Float16 fp16;
typedef __attribute__((ext_vector_type(4))) _Float16 f16x4;
typedef __attribute__((ext_vector_type(8))) _Float16 f16x8;
typedef __attribute__((ext_vector_type(4))) float floatx4;

// ---------------------------------------------------------------------------
// R0-proven gelu: 6-term Taylor erf on |t|<=0.5 (abs err <= 1.5e-8), erff
// fallback for rare outliers. (R4 measured a branchless exp-based variant at
// +21% kernel time — trans-pipe links in the epilogue chain are poison.)
// ---------------------------------------------------------------------------
__device__ __forceinline__ float gelu_exact(float x) {
    float tt = x * 0.70710678118654752440f;
    float e;
    if (__builtin_expect(fabsf(tt) > 0.5f, 0)) {
        e = erff(tt);
    } else {
        float s = tt * tt;
        e = tt * fmaf(s, fmaf(s, fmaf(s, fmaf(s, fmaf(s,
                -8.548327023450852e-4f, 5.223977625442188e-3f),
                -2.6866170645131252e-2f), 0.11283791670955126f),
                -0.3761263890318375f), 1.1283791670955126f);
    }
    return 0.5f * x * (1.0f + e);
}

// ---------------------------------------------------------------------------
// fp16 DUAL split: h = fp16(x) (11-bit mantissa), m = fp16(x - h). h+m covers
// ~22 mantissa bits; fp16*fp16 products are EXACT in the fp32 MFMA
// accumulator, so 4 cross-products give ~2^-22 rel error (R5-verified).
// ---------------------------------------------------------------------------
__device__ __forceinline__ void split2(float a, fp16& h, fp16& m) {
    h = (fp16)a;
    m = (fp16)(a - (float)h);
}

// ---------------------------------------------------------------------------
// Dual-split into MFMA frag-major order for [512][512] matrices; 5 matrices
// batched via blockIdx.z. (row,k) -> ((rt*16+ks)*64 + q4*16 + rm)*8 + u.
// ---------------------------------------------------------------------------
struct SplitArgs {
    const float* src[5];
    fp16* h[5]; fp16* m[5];
};

__global__ __launch_bounds__(256) void split2_512_kernel(SplitArgs S) {
    int z = blockIdx.z;
    const float* src = S.src[z];
    fp16* dh = S.h[z]; fp16* dm = S.m[z];
    int t = blockIdx.x * 256 + threadIdx.x;
    int row = t >> 7, kq = (t & 127) * 4;
    int rt = row >> 4, rm = row & 15;
    int ks = kq >> 5, q4 = (kq >> 3) & 3, u0 = kq & 7;
    int dst = ((rt * 16 + ks) * 64 + q4 * 16 + rm) * 8 + u0;
    float4 vv = *(const float4*)&src[row * 512 + kq];
    float a4[4] = {vv.x, vv.y, vv.z, vv.w};
    f16x4 h, m;
    #pragma unroll
    for (int u = 0; u < 4; u++) {
        fp16 hh, mm;
        split2(a4[u], hh, mm);
        h[u] = hh; m[u] = mm;
    }
    *(f16x4*)&dh[dst] = h;
    *(f16x4*)&dm[dst] = m;
}

// ---------------------------------------------------------------------------
// C = A @ W^T + bias via dual-split fp16 MFMA (R5-proven). One wave per block
// computing a 16x16 tile; grid (32, 32, nz). 4 MFMAs per k-step in two
// independent 2-chains. mode 0: fp32 [m*512+n]; mode 1: heads fp32 (b,h,c,d);
// mode 2: K written directly as frag-major dual-split.
// ---------------------------------------------------------------------------
struct MM2Args {
    const fp16 *Ah, *Am;
    const fp16 *Wh[3], *Wm[3];
    const float* bias[3];
    float* outf[3];
    fp16 *kh, *km;
    int mode[3];
};

__global__ __launch_bounds__(64) void mm_mfma_kernel(MM2Args A) {
    const int z = blockIdx.z;
    const fp16* Wh = A.Wh[z]; const fp16* Wm = A.Wm[z];
    const float* bias = A.bias[z];
    const int lane = threadIdx.x;
    const int m16 = lane & 15, q4 = lane >> 4;
    const int mt = blockIdx.y, bx = blockIdx.x;

    floatx4 acc0, acc1;
    {
        float bv = bias[bx * 16 + m16];
        acc0[0] = bv; acc0[1] = bv; acc0[2] = bv; acc0[3] = bv;
        acc1[0] = 0.f; acc1[1] = 0.f; acc1[2] = 0.f; acc1[3] = 0.f;
    }

    #pragma unroll 4
    for (int ks = 0; ks < 16; ks++) {
        int sa = ((mt * 16 + ks) * 64 + lane) * 8;
        f16x8 ah = *(const f16x8*)&A.Ah[sa];
        f16x8 am = *(const f16x8*)&A.Am[sa];
        int sw = ((bx * 16 + ks) * 64 + lane) * 8;
        f16x8 wh = *(const f16x8*)&Wh[sw];
        f16x8 wm = *(const f16x8*)&Wm[sw];
        acc0 = __builtin_amdgcn_mfma_f32_16x16x32_f16(ah, wh, acc0, 0, 0, 0);
        acc1 = __builtin_amdgcn_mfma_f32_16x16x32_f16(ah, wm, acc1, 0, 0, 0);
        acc0 = __builtin_amdgcn_mfma_f32_16x16x32_f16(am, wh, acc0, 0, 0, 0);
        acc1 = __builtin_amdgcn_mfma_f32_16x16x32_f16(am, wm, acc1, 0, 0, 0);
    }
    floatx4 acc = acc0 + acc1;

    const int mode = A.mode[z];
    const int n = bx * 16 + m16;
    #pragma unroll
    for (int r = 0; r < 4; r++) {
        int m = mt * 16 + q4 * 4 + r;
        float val = acc[r];
        if (mode == 0) {
            A.outf[z][m * 512 + n] = val;
        } else if (mode == 1) {
            A.outf[z][(((m >> 8) * 8 + (n >> 6)) * 256 + (m & 255)) * 64 + (n & 63)] = val;
        } else {
            int krow = ((m >> 8) * 8 + (n >> 6)) * 256 + (m & 255);
            int d = n & 63;
            int dst = (((krow >> 4) * 2 + (d >> 5)) * 64 + ((d >> 3) & 3) * 16 + (krow & 15)) * 8 + (d & 7);
            fp16 h, mm;
            split2(val, h, mm);
            A.kh[dst] = h; A.km[dst] = mm;
        }
    }
}

// ---------------------------------------------------------------------------
// Fused per-(bh, i-pair). R6: express ILP by hand — 5 rounds proved fused
// time is invariant to instruction COUNT (R1 -35% VALU flat, R5 -33% MFMA
// flat) but sensitive to chain DEPTH (R4 +2 trans links = +19us). So:
//  - the two independent i01 MFMA chains are interleaved (4 independent
//    4-chains live at once instead of 2 sequential pairs)
//  - both epilogues interleaved (8 independent gelus, 2 indep shfl chains)
//  - explicit K-tile prefetch, distance 1 (next jt's 4 loads issued before
//    this jt's MFMAs -> a full iteration of latency cover)
//  - attn@V unrolled x2 with dual accumulator pairs (8 V-loads in flight)
// Register estimate ~100-110 <= (256,4) budget of 128 -> no spill expected.
// ---------------------------------------------------------------------------
__global__ __launch_bounds__(256, 4) void fused_mfma_attn_kernel(
    const float* __restrict__ q, const float* __restrict__ v,
    const fp16* __restrict__ khi, const fp16* __restrict__ kmid,
    const float* __restrict__ w1, const float* __restrict__ b1,
    const float* __restrict__ w2, const float* __restrict__ b2,
    fp16* __restrict__ oh, fp16* __restrict__ om)
{
    const int i2 = blockIdx.x;     // query pair: i = 2*i2 + i01
    const int bh = blockIdx.y;
    const int t  = threadIdx.x;
    const int lane = t & 63, w = t >> 6;
    const int m16 = lane & 15, q4 = lane >> 4;

    __shared__ float part[2][4][256];   // per-wave f-partials of scores
    __shared__ float sc[2][256];        // softmax probabilities
    __shared__ float qpb_s[2][64];
    __shared__ float sbuf[2][256];      // bitonic cross-wave exchange
    __shared__ float red[2][4][64];
    __shared__ float red2[2][4];
    __shared__ float thr_s[2], smax_s[2];

    const int f = w * 16 + m16;         // this lane's f (A-operand M index)
    const float* w1row = w1 + f * 192;

    // ---- build A_i fragments in registers + qpb
    f16x8 Ah[2][2], Am[2][2];
    #pragma unroll
    for (int i01 = 0; i01 < 2; i01++) {
        const float* qrow = q + (bh * 256 + i2 * 2 + i01) * 64;
        float qa = 0.f;
        #pragma unroll
        for (int ks = 0; ks < 2; ks++) {
            int e0 = ks * 32 + q4 * 8;
            #pragma unroll
            for (int u = 0; u < 2; u++) {
                int e = e0 + u * 4;
                float4 wa = *(const float4*)&w1row[e];
                float4 wb = *(const float4*)&w1row[64 + e];
                float4 wc = *(const float4*)&w1row[128 + e];
                float4 qv = *(const float4*)&qrow[e];
                qa += wa.x * qv.x + wa.y * qv.y + wa.z * qv.z + wa.w * qv.w;
                float av[4];
                av[0] = fmaf(wc.x, qv.x, wb.x);
                av[1] = fmaf(wc.y, qv.y, wb.y);
                av[2] = fmaf(wc.z, qv.z, wb.z);
                av[3] = fmaf(wc.w, qv.w, wb.w);
                #pragma unroll
                for (int uu = 0; uu < 4; uu++) {
                    fp16 h, m;
                    split2(av[uu], h, m);
                    Ah[i01][ks][u * 4 + uu] = h;
                    Am[i01][ks][u * 4 + uu] = m;
                }
            }
        }
        qa += __shfl_xor(qa, 16);
        qa += __shfl_xor(qa, 32);
        if (lane < 16) qpb_s[i01][w * 16 + lane] = qa + b1[w * 16 + lane];
    }
    __syncthreads();

    floatx4 qpbr[2];
    qpbr[0] = *(const floatx4*)&qpb_s[0][w * 16 + q4 * 4];
    qpbr[1] = *(const floatx4*)&qpb_s[1][w * 16 + q4 * 4];
    const float4 w2f = *(const float4*)&w2[w * 16 + q4 * 4];
    const float b2v = b2[0];

    // ---- main loop over j-tiles: prefetched K, 4 interleaved MFMA chains
    {
        int base = ((bh * 16) * 2 * 64 + lane) * 8;
        f16x8 Kh0 = *(const f16x8*)&khi [base];
        f16x8 Km0 = *(const f16x8*)&kmid[base];
        f16x8 Kh1 = *(const f16x8*)&khi [base + 512];
        f16x8 Km1 = *(const f16x8*)&kmid[base + 512];
        #pragma unroll 1
        for (int jt = 0; jt < 16; jt++) {
            f16x8 nKh0, nKm0, nKh1, nKm1;
            if (jt < 15) {
                int nb = ((bh * 16 + jt + 1) * 2 * 64 + lane) * 8;
                nKh0 = *(const f16x8*)&khi [nb];
                nKm0 = *(const f16x8*)&kmid[nb];
                nKh1 = *(const f16x8*)&khi [nb + 512];
                nKm1 = *(const f16x8*)&kmid[nb + 512];
            }
            floatx4 a0 = qpbr[0], a1 = qpbr[1];
            floatx4 b0, b1v_;
            b0[0] = 0.f; b0[1] = 0.f; b0[2] = 0.f; b0[3] = 0.f;
            b1v_ = b0;
            // 16 MFMAs as 4 independent 4-chains, round-robin issued
            a0   = __builtin_amdgcn_mfma_f32_16x16x32_f16(Ah[0][0], Kh0, a0,   0, 0, 0);
            a1   = __builtin_amdgcn_mfma_f32_16x16x32_f16(Ah[1][0], Kh0, a1,   0, 0, 0);
            b0   = __builtin_amdgcn_mfma_f32_16x16x32_f16(Ah[0][0], Km0, b0,   0, 0, 0);
            b1v_ = __builtin_amdgcn_mfma_f32_16x16x32_f16(Ah[1][0], Km0, b1v_, 0, 0, 0);
            a0   = __builtin_amdgcn_mfma_f32_16x16x32_f16(Am[0][0], Kh0, a0,   0, 0, 0);
            a1   = __builtin_amdgcn_mfma_f32_16x16x32_f16(Am[1][0], Kh0, a1,   0, 0, 0);
            b0   = __builtin_amdgcn_mfma_f32_16x16x32_f16(Am[0][0], Km0, b0,   0, 0, 0);
            b1v_ = __builtin_amdgcn_mfma_f32_16x16x32_f16(Am[1][0], Km0, b1v_, 0, 0, 0);
            a0   = __builtin_amdgcn_mfma_f32_16x16x32_f16(Ah[0][1], Kh1, a0,   0, 0, 0);
            a1   = __builtin_amdgcn_mfma_f32_16x16x32_f16(Ah[1][1], Kh1, a1,   0, 0, 0);
            b0   = __builtin_amdgcn_mfma_f32_16x16x32_f16(Ah[0][1], Km1, b0,   0, 0, 0);
            b1v_ = __builtin_amdgcn_mfma_f32_16x16x32_f16(Ah[1][1], Km1, b1v_, 0, 0, 0);
            a0   = __builtin_amdgcn_mfma_f32_16x16x32_f16(Am[0][1], Kh1, a0,   0, 0, 0);
            a1   = __builtin_amdgcn_mfma_f32_16x16x32_f16(Am[1][1], Kh1, a1,   0, 0, 0);
            b0   = __builtin_amdgcn_mfma_f32_16x16x32_f16(Am[0][1], Km1, b0,   0, 0, 0);
            b1v_ = __builtin_amdgcn_mfma_f32_16x16x32_f16(Am[1][1], Km1, b1v_, 0, 0, 0);
            a0 = a0 + b0; a1 = a1 + b1v_;
            // 8 independent gelus, then two independent reduce chains
            float g00 = gelu_exact(a0[0]);
            float g10 = gelu_exact(a1[0]);
            float g01 = gelu_exact(a0[1]);
            float g11 = gelu_exact(a1[1]);
            float g02 = gelu_exact(a0[2]);
            float g12 = gelu_exact(a1[2]);
            float g03 = gelu_exact(a0[3]);
            float g13 = gelu_exact(a1[3]);
            float s0a = fmaf(w2f.y, g01, w2f.x * g00);
            float s1a = fmaf(w2f.y, g11, w2f.x * g10);
            float s0b = fmaf(w2f.w, g03, w2f.z * g02);
            float s1b = fmaf(w2f.w, g13, w2f.z * g12);
            float s0 = s0a + s0b;
            float s1 = s1a + s1b;
            s0 += __shfl_xor(s0, 16);
            s1 += __shfl_xor(s1, 16);
            s0 += __shfl_xor(s0, 32);
            s1 += __shfl_xor(s1, 32);
            if (lane < 16) {
                part[0][w][jt * 16 + lane] = s0;
                part[1][w][jt * 16 + lane] = s1;
            }
            Kh0 = nKh0; Km0 = nKm0; Kh1 = nKh1; Km1 = nKm1;
        }
    }
    __syncthreads();

    // ---- scores
    float score[2];
    #pragma unroll
    for (int i01 = 0; i01 < 2; i01++) {
        score[i01] = (((part[i01][0][t] + part[i01][1][t]) +
                       (part[i01][2][t] + part[i01][3][t])) + b2v) * 0.125f;
    }

    // ---- dual lockstep 256-wide bitonic sort; sorted[192] = 64th largest.
    float sv0 = score[0], sv1 = score[1];
    #pragma unroll
    for (int k = 2; k <= 256; k <<= 1) {
        #pragma unroll
        for (int j = k >> 1; j >= 1; j >>= 1) {
            float pv0, pv1;
            if (j >= 64) {
                sbuf[0][t] = sv0; sbuf[1][t] = sv1;
                __syncthreads();
                pv0 = sbuf[0][t ^ j]; pv1 = sbuf[1][t ^ j];
                __syncthreads();
            } else {
                pv0 = __shfl_xor(sv0, j);
                pv1 = __shfl_xor(sv1, j);
            }
            bool keepMin = (((t & j) == 0) == ((t & k) == 0));
            sv0 = keepMin ? fminf(sv0, pv0) : fmaxf(sv0, pv0);
            sv1 = keepMin ? fminf(sv1, pv1) : fmaxf(sv1, pv1);
        }
    }
    if (t == 192) { thr_s[0] = sv0; thr_s[1] = sv1; }
    if (t == 255) { smax_s[0] = sv0; smax_s[1] = sv1; }
    __syncthreads();

    // ---- softmax numerator + denominator
    float p0 = (score[0] >= thr_s[0]) ? __expf(score[0] - smax_s[0]) : 0.0f;
    float p1 = (score[1] >= thr_s[1]) ? __expf(score[1] - smax_s[1]) : 0.0f;
    sc[0][t] = p0; sc[1][t] = p1;
    float ps0 = p0, ps1 = p1;
    #pragma unroll
    for (int mask = 1; mask < 64; mask <<= 1) {
        ps0 += __shfl_xor(ps0, mask);
        ps1 += __shfl_xor(ps1, mask);
    }
    if (lane == 0) { red2[0][w] = ps0; red2[1][w] = ps1; }
    __syncthreads();
    const float inv0 = 1.0f / ((red2[0][0] + red2[0][1]) + (red2[0][2] + red2[0][3]));
    const float inv1 = 1.0f / ((red2[1][0] + red2[1][1]) + (red2[1][2] + red2[1][3]));

    // ---- attn @ V: unrolled x2, dual accumulator pairs (8 loads in flight)
    const int d = t & 63, g = t >> 6;
    const float* vb = v + bh * 256 * 64;
    float a0 = 0.f, a1 = 0.f, a0b = 0.f, a1b = 0.f;
    for (int j8 = 0; j8 < 8; j8++) {
        int jj = g * 64 + j8 * 8;
        float4 p40 = *(const float4*)&sc[0][jj];
        float4 p41 = *(const float4*)&sc[1][jj];
        float4 p42 = *(const float4*)&sc[0][jj + 4];
        float4 p43 = *(const float4*)&sc[1][jj + 4];
        float v0 = vb[(jj + 0) * 64 + d];
        float v1 = vb[(jj + 1) * 64 + d];
        float v2 = vb[(jj + 2) * 64 + d];
        float v3 = vb[(jj + 3) * 64 + d];
        float v4 = vb[(jj + 4) * 64 + d];
        float v5 = vb[(jj + 5) * 64 + d];
        float v6 = vb[(jj + 6) * 64 + d];
        float v7 = vb[(jj + 7) * 64 + d];
        a0  = fmaf(p40.x, v0, a0);  a1  = fmaf(p41.x, v0, a1);
        a0b = fmaf(p42.x, v4, a0b); a1b = fmaf(p43.x, v4, a1b);
        a0  = fmaf(p40.y, v1, a0);  a1  = fmaf(p41.y, v1, a1);
        a0b = fmaf(p42.y, v5, a0b); a1b = fmaf(p43.y, v5, a1b);
        a0  = fmaf(p40.z, v2, a0);  a1  = fmaf(p41.z, v2, a1);
        a0b = fmaf(p42.z, v6, a0b); a1b = fmaf(p43.z, v6, a1b);
        a0  = fmaf(p40.w, v3, a0);  a1  = fmaf(p41.w, v3, a1);
        a0b = fmaf(p42.w, v7, a0b); a1b = fmaf(p43.w, v7, a1b);
    }
    red[0][g][d] = a0 + a0b; red[1][g][d] = a1 + a1b;
    __syncthreads();

    // ---- output: (B,H,C,D)->(B,C,DM) row, written as dual-split frag-major
    if (t < 128) {
        int i01 = t >> 6, dd = t & 63;
        float o = ((red[i01][0][dd] + red[i01][1][dd]) +
                   (red[i01][2][dd] + red[i01][3][dd])) * (i01 ? inv1 : inv0);
        int b = bh >> 3, h = bh & 7;
        int row = b * 256 + i2 * 2 + i01;
        int n = h * 64 + dd;
        int dst = (((row >> 4) * 16 + (n >> 5)) * 64 + ((n >> 3) & 3) * 16 + (row & 15)) * 8 + (n & 7);
        fp16 hh, mm;
        split2(o, hh, mm);
        oh[dst] = hh; om[dst] = mm;
    }
}

// ---------------------------------------------------------------------------
extern "C" void kernel_launch(void* const* d_in, const int* in_sizes, int n_in,
                              void* d_out, int out_size, void* d_ws, size_t ws_size,
                              hipStream_t stream) {
    const float* x  = (const float*)d_in[0];
    const float* Wq = (const float*)d_in[1];
    const float* bq = (const float*)d_in[2];
    const float* Wk = (const float*)d_in[3];
    const float* bk = (const float*)d_in[4];
    const float* Wv = (const float*)d_in[5];
    const float* bv = (const float*)d_in[6];
    const float* w1 = (const float*)d_in[7];
    const float* b1 = (const float*)d_in[8];
    const float* w2 = (const float*)d_in[9];
    const float* b2 = (const float*)d_in[10];
    const float* Wo = (const float*)d_in[11];
    const float* bo = (const float*)d_in[12];
    float* out = (float*)d_out;

    const int NE = 262144;   // 512*512
    float* qb  = (float*)d_ws;          // q (b,h,c,d) fp32
    float* vb  = qb + NE;               // v (b,h,c,d) fp32
    fp16* base = (fp16*)(vb + NE);
    fp16* khi  = base;            fp16* kmid = khi + NE;
    fp16* xs   = kmid + NE;       // hi/mid duals follow (2*NE each)
    fp16* wqs  = xs  + 2 * NE;
    fp16* wks  = wqs + 2 * NE;
    fp16* wvs  = wks + 2 * NE;
    fp16* wos  = wvs + 2 * NE;
    fp16* oas  = wos + 2 * NE;

    // 1) split x, Wq, Wk, Wv, Wo into frag-major fp16 duals
    {
        SplitArgs S;
        const float* srcs[5] = {x, Wq, Wk, Wv, Wo};
        fp16* dsts[5] = {xs, wqs, wks, wvs, wos};
        for (int z = 0; z < 5; z++) {
            S.src[z] = srcs[z];
            S.h[z] = dsts[z]; S.m[z] = dsts[z] + NE;
        }
        split2_512_kernel<<<dim3(256, 1, 5), 256, 0, stream>>>(S);
    }
    // 2) QKV projections; K written directly as dual-split frag-major
    {
        MM2Args M;
        M.Ah = xs; M.Am = xs + NE;
        M.Wh[0] = wqs; M.Wm[0] = wqs + NE;
        M.Wh[1] = wks; M.Wm[1] = wks + NE;
        M.Wh[2] = wvs; M.Wm[2] = wvs + NE;
        M.bias[0] = bq; M.bias[1] = bk; M.bias[2] = bv;
        M.outf[0] = qb; M.outf[1] = nullptr; M.outf[2] = vb;
        M.kh = khi; M.km = kmid;
        M.mode[0] = 1; M.mode[1] = 2; M.mode[2] = 1;
        mm_mfma_kernel<<<dim3(32, 32, 3), 64, 0, stream>>>(M);
    }
    // 3) fused second-order scores + top-64 + softmax + attn@V (+ dual out)
    fused_mfma_attn_kernel<<<dim3(128, 16), 256, 0, stream>>>(
        qb, vb, khi, kmid, w1, b1, w2, b2,
        oas, oas + NE);
    // 4) output projection
    {
        MM2Args M;
        M.Ah = oas; M.Am = oas + NE;
        M.Wh[0] = wos; M.Wm[0] = wos + NE;
        M.Wh[1] = wos; M.Wm[1] = wos;
        M.Wh[2] = wos; M.Wm[2] = wos;
        M.bias[0] = bo; M.bias[1] = bo; M.bias[2] = bo;
        M.outf[0] = out; M.outf[1] = out; M.outf[2] = out;
        M.kh = khi; M.km = kmid;
        M.mode[0] = 0; M.mode[1] = 0; M.mode[2] = 0;
        mm_mfma_kernel<<<dim3(32, 32, 1), 64, 0, stream>>>(M);
    }
}

// Round 7
// 173.235 us; speedup vs baseline: 1.1397x; 1.0098x over previous
//
#include <hip/hip_runtime.h>
#include <math.h>

// Problem constants: B=2, C=256, DM=512, H=8, D=64, SPARSE_K=64
typedef _Float16 fp16;
typedef __attribute__((ext_vector_type(4))) _Float16 f16x4;
typedef __attribute__((ext_vector_type(8))) _Float16 f16x8;
typedef __attribute__((ext_vector_type(4))) float floatx4;
typedef __attribute__((ext_vector_type(2))) float f32x2;

__device__ __forceinline__ f32x2 mk2(float a, float b) { f32x2 r; r.x = a; r.y = b; return r; }
__device__ __forceinline__ f32x2 sp2(float a) { f32x2 r; r.x = a; r.y = a; return r; }

// ---------------------------------------------------------------------------
// Packed-pair gelu (R1-proven lowering to v_pk_fma_f32): 6-term Taylor erf on
// |t|<=0.5 (abs err <= 1.5e-8), erff fallback for rare outliers. Packs the
// two independent queries (i0,i1) — halves VALU issue count vs scalar. R6
// proved the chains are now overlapped, so issue count is the binding term.
// ---------------------------------------------------------------------------
__device__ __forceinline__ f32x2 gelu2(f32x2 x) {
    f32x2 tt = x * 0.70710678118654752440f;
    f32x2 s  = tt * tt;
    f32x2 p  = __builtin_elementwise_fma(s, sp2(-8.548327023450852e-4f), sp2(5.223977625442188e-3f));
    p = __builtin_elementwise_fma(s, p, sp2(-2.6866170645131252e-2f));
    p = __builtin_elementwise_fma(s, p, sp2(0.11283791670955126f));
    p = __builtin_elementwise_fma(s, p, sp2(-0.3761263890318375f));
    p = __builtin_elementwise_fma(s, p, sp2(1.1283791670955126f));
    f32x2 e = tt * p;
    if (__builtin_expect(fabsf(tt.x) > 0.5f, 0)) e.x = erff(tt.x);
    if (__builtin_expect(fabsf(tt.y) > 0.5f, 0)) e.y = erff(tt.y);
    f32x2 hx = x * 0.5f;
    return __builtin_elementwise_fma(hx, e, hx);   // 0.5x + 0.5x*e
}

// ---------------------------------------------------------------------------
// fp16 DUAL split: h = fp16(x) (11-bit mantissa), m = fp16(x - h). h+m covers
// ~22 mantissa bits; fp16*fp16 products are EXACT in the fp32 MFMA
// accumulator, so 4 cross-products give ~2^-22 rel error (R5-verified).
// ---------------------------------------------------------------------------
__device__ __forceinline__ void split2(float a, fp16& h, fp16& m) {
    h = (fp16)a;
    m = (fp16)(a - (float)h);
}

// ---------------------------------------------------------------------------
// Dual-split into MFMA frag-major order for [512][512] matrices; 5 matrices
// batched via blockIdx.z. (row,k) -> ((rt*16+ks)*64 + q4*16 + rm)*8 + u.
// ---------------------------------------------------------------------------
struct SplitArgs {
    const float* src[5];
    fp16* h[5]; fp16* m[5];
};

__global__ __launch_bounds__(256) void split2_512_kernel(SplitArgs S) {
    int z = blockIdx.z;
    const float* src = S.src[z];
    fp16* dh = S.h[z]; fp16* dm = S.m[z];
    int t = blockIdx.x * 256 + threadIdx.x;
    int row = t >> 7, kq = (t & 127) * 4;
    int rt = row >> 4, rm = row & 15;
    int ks = kq >> 5, q4 = (kq >> 3) & 3, u0 = kq & 7;
    int dst = ((rt * 16 + ks) * 64 + q4 * 16 + rm) * 8 + u0;
    float4 vv = *(const float4*)&src[row * 512 + kq];
    float a4[4] = {vv.x, vv.y, vv.z, vv.w};
    f16x4 h, m;
    #pragma unroll
    for (int u = 0; u < 4; u++) {
        fp16 hh, mm;
        split2(a4[u], hh, mm);
        h[u] = hh; m[u] = mm;
    }
    *(f16x4*)&dh[dst] = h;
    *(f16x4*)&dm[dst] = m;
}

// ---------------------------------------------------------------------------
// C = A @ W^T + bias via dual-split fp16 MFMA (R5-proven). One wave per block
// computing a 16x16 tile; grid (32, 32, nz). 4 MFMAs per k-step in two
// independent 2-chains. mode 0: fp32 [m*512+n]; mode 1: heads fp32 (b,h,c,d);
// mode 2: K written directly as frag-major dual-split.
// ---------------------------------------------------------------------------
struct MM2Args {
    const fp16 *Ah, *Am;
    const fp16 *Wh[3], *Wm[3];
    const float* bias[3];
    float* outf[3];
    fp16 *kh, *km;
    int mode[3];
};

__global__ __launch_bounds__(64) void mm_mfma_kernel(MM2Args A) {
    const int z = blockIdx.z;
    const fp16* Wh = A.Wh[z]; const fp16* Wm = A.Wm[z];
    const float* bias = A.bias[z];
    const int lane = threadIdx.x;
    const int m16 = lane & 15, q4 = lane >> 4;
    const int mt = blockIdx.y, bx = blockIdx.x;

    floatx4 acc0, acc1;
    {
        float bv = bias[bx * 16 + m16];
        acc0[0] = bv; acc0[1] = bv; acc0[2] = bv; acc0[3] = bv;
        acc1[0] = 0.f; acc1[1] = 0.f; acc1[2] = 0.f; acc1[3] = 0.f;
    }

    #pragma unroll 4
    for (int ks = 0; ks < 16; ks++) {
        int sa = ((mt * 16 + ks) * 64 + lane) * 8;
        f16x8 ah = *(const f16x8*)&A.Ah[sa];
        f16x8 am = *(const f16x8*)&A.Am[sa];
        int sw = ((bx * 16 + ks) * 64 + lane) * 8;
        f16x8 wh = *(const f16x8*)&Wh[sw];
        f16x8 wm = *(const f16x8*)&Wm[sw];
        acc0 = __builtin_amdgcn_mfma_f32_16x16x32_f16(ah, wh, acc0, 0, 0, 0);
        acc1 = __builtin_amdgcn_mfma_f32_16x16x32_f16(ah, wm, acc1, 0, 0, 0);
        acc0 = __builtin_amdgcn_mfma_f32_16x16x32_f16(am, wh, acc0, 0, 0, 0);
        acc1 = __builtin_amdgcn_mfma_f32_16x16x32_f16(am, wm, acc1, 0, 0, 0);
    }
    floatx4 acc = acc0 + acc1;

    const int mode = A.mode[z];
    const int n = bx * 16 + m16;
    #pragma unroll
    for (int r = 0; r < 4; r++) {
        int m = mt * 16 + q4 * 4 + r;
        float val = acc[r];
        if (mode == 0) {
            A.outf[z][m * 512 + n] = val;
        } else if (mode == 1) {
            A.outf[z][(((m >> 8) * 8 + (n >> 6)) * 256 + (m & 255)) * 64 + (n & 63)] = val;
        } else {
            int krow = ((m >> 8) * 8 + (n >> 6)) * 256 + (m & 255);
            int d = n & 63;
            int dst = (((krow >> 4) * 2 + (d >> 5)) * 64 + ((d >> 3) & 3) * 16 + (krow & 15)) * 8 + (d & 7);
            fp16 h, mm;
            split2(val, h, mm);
            A.kh[dst] = h; A.km[dst] = mm;
        }
    }
}

// ---------------------------------------------------------------------------
// Fused per-(bh, i-pair). R7 = R6 interleave + R1 packing, composed:
// Ledger: R1 (pack, no ILP) flat -> latency-bound; R6 (ILP, no pack) -11.5%
// -> chains broken, VALUBusy now 52% = issue is the new binder; R7 packs all
// post-MFMA math into f32x2 (i0,i1) pairs to halve VALU issue:
//  - 4 independent packed gelu2 chains per jt (was 8 scalar)
//  - packed score reduce / bitonic sort / softmax / attn@V
//  - MFMA round-robin interleave + K-prefetch(1) unchanged from R6
// ---------------------------------------------------------------------------
__global__ __launch_bounds__(256, 4) void fused_mfma_attn_kernel(
    const float* __restrict__ q, const float* __restrict__ v,
    const fp16* __restrict__ khi, const fp16* __restrict__ kmid,
    const float* __restrict__ w1, const float* __restrict__ b1,
    const float* __restrict__ w2, const float* __restrict__ b2,
    fp16* __restrict__ oh, fp16* __restrict__ om)
{
    const int i2 = blockIdx.x;     // query pair: i = 2*i2 + i01
    const int bh = blockIdx.y;
    const int t  = threadIdx.x;
    const int lane = t & 63, w = t >> 6;
    const int m16 = lane & 15, q4 = lane >> 4;

    __shared__ f32x2 part2[4][256];    // per-wave f-partials (pair = i0,i1)
    __shared__ f32x2 sc2[256];         // softmax probabilities (pair)
    __shared__ float qpb_s[2][64];
    __shared__ f32x2 sbuf2[256];       // bitonic cross-wave exchange (pair)
    __shared__ f32x2 red_s[4][64];     // attn@V partials (pair)
    __shared__ f32x2 red2_s[4];
    __shared__ f32x2 thr_s2, smax_s2;

    const int f = w * 16 + m16;         // this lane's f (A-operand M index)
    const float* w1row = w1 + f * 192;

    // ---- build A_i fragments in registers + qpb
    f16x8 Ah[2][2], Am[2][2];
    #pragma unroll
    for (int i01 = 0; i01 < 2; i01++) {
        const float* qrow = q + (bh * 256 + i2 * 2 + i01) * 64;
        float qa = 0.f;
        #pragma unroll
        for (int ks = 0; ks < 2; ks++) {
            int e0 = ks * 32 + q4 * 8;
            #pragma unroll
            for (int u = 0; u < 2; u++) {
                int e = e0 + u * 4;
                float4 wa = *(const float4*)&w1row[e];
                float4 wb = *(const float4*)&w1row[64 + e];
                float4 wc = *(const float4*)&w1row[128 + e];
                float4 qv = *(const float4*)&qrow[e];
                qa += wa.x * qv.x + wa.y * qv.y + wa.z * qv.z + wa.w * qv.w;
                float av[4];
                av[0] = fmaf(wc.x, qv.x, wb.x);
                av[1] = fmaf(wc.y, qv.y, wb.y);
                av[2] = fmaf(wc.z, qv.z, wb.z);
                av[3] = fmaf(wc.w, qv.w, wb.w);
                #pragma unroll
                for (int uu = 0; uu < 4; uu++) {
                    fp16 h, m;
                    split2(av[uu], h, m);
                    Ah[i01][ks][u * 4 + uu] = h;
                    Am[i01][ks][u * 4 + uu] = m;
                }
            }
        }
        qa += __shfl_xor(qa, 16);
        qa += __shfl_xor(qa, 32);
        if (lane < 16) qpb_s[i01][w * 16 + lane] = qa + b1[w * 16 + lane];
    }
    __syncthreads();

    floatx4 qpbr[2];
    qpbr[0] = *(const floatx4*)&qpb_s[0][w * 16 + q4 * 4];
    qpbr[1] = *(const floatx4*)&qpb_s[1][w * 16 + q4 * 4];
    const float4 w2f = *(const float4*)&w2[w * 16 + q4 * 4];
    const float b2v = b2[0];

    // ---- main loop: prefetched K, 4 interleaved MFMA chains, packed epilogue
    {
        int base = ((bh * 16) * 2 * 64 + lane) * 8;
        f16x8 Kh0 = *(const f16x8*)&khi [base];
        f16x8 Km0 = *(const f16x8*)&kmid[base];
        f16x8 Kh1 = *(const f16x8*)&khi [base + 512];
        f16x8 Km1 = *(const f16x8*)&kmid[base + 512];
        #pragma unroll 1
        for (int jt = 0; jt < 16; jt++) {
            f16x8 nKh0, nKm0, nKh1, nKm1;
            if (jt < 15) {
                int nb = ((bh * 16 + jt + 1) * 2 * 64 + lane) * 8;
                nKh0 = *(const f16x8*)&khi [nb];
                nKm0 = *(const f16x8*)&kmid[nb];
                nKh1 = *(const f16x8*)&khi [nb + 512];
                nKm1 = *(const f16x8*)&kmid[nb + 512];
            }
            floatx4 a0 = qpbr[0], a1 = qpbr[1];
            floatx4 b0, b1v_;
            b0[0] = 0.f; b0[1] = 0.f; b0[2] = 0.f; b0[3] = 0.f;
            b1v_ = b0;
            // 16 MFMAs as 4 independent 4-chains, round-robin issued
            a0   = __builtin_amdgcn_mfma_f32_16x16x32_f16(Ah[0][0], Kh0, a0,   0, 0, 0);
            a1   = __builtin_amdgcn_mfma_f32_16x16x32_f16(Ah[1][0], Kh0, a1,   0, 0, 0);
            b0   = __builtin_amdgcn_mfma_f32_16x16x32_f16(Ah[0][0], Km0, b0,   0, 0, 0);
            b1v_ = __builtin_amdgcn_mfma_f32_16x16x32_f16(Ah[1][0], Km0, b1v_, 0, 0, 0);
            a0   = __builtin_amdgcn_mfma_f32_16x16x32_f16(Am[0][0], Kh0, a0,   0, 0, 0);
            a1   = __builtin_amdgcn_mfma_f32_16x16x32_f16(Am[1][0], Kh0, a1,   0, 0, 0);
            b0   = __builtin_amdgcn_mfma_f32_16x16x32_f16(Am[0][0], Km0, b0,   0, 0, 0);
            b1v_ = __builtin_amdgcn_mfma_f32_16x16x32_f16(Am[1][0], Km0, b1v_, 0, 0, 0);
            a0   = __builtin_amdgcn_mfma_f32_16x16x32_f16(Ah[0][1], Kh1, a0,   0, 0, 0);
            a1   = __builtin_amdgcn_mfma_f32_16x16x32_f16(Ah[1][1], Kh1, a1,   0, 0, 0);
            b0   = __builtin_amdgcn_mfma_f32_16x16x32_f16(Ah[0][1], Km1, b0,   0, 0, 0);
            b1v_ = __builtin_amdgcn_mfma_f32_16x16x32_f16(Ah[1][1], Km1, b1v_, 0, 0, 0);
            a0   = __builtin_amdgcn_mfma_f32_16x16x32_f16(Am[0][1], Kh1, a0,   0, 0, 0);
            a1   = __builtin_amdgcn_mfma_f32_16x16x32_f16(Am[1][1], Kh1, a1,   0, 0, 0);
            b0   = __builtin_amdgcn_mfma_f32_16x16x32_f16(Am[0][1], Km1, b0,   0, 0, 0);
            b1v_ = __builtin_amdgcn_mfma_f32_16x16x32_f16(Am[1][1], Km1, b1v_, 0, 0, 0);
            a0 = a0 + b0; a1 = a1 + b1v_;
            // packed epilogue: 4 independent gelu2 chains on (i0,i1) pairs
            f32x2 g0 = gelu2(mk2(a0[0], a1[0]));
            f32x2 g1 = gelu2(mk2(a0[1], a1[1]));
            f32x2 g2 = gelu2(mk2(a0[2], a1[2]));
            f32x2 g3 = gelu2(mk2(a0[3], a1[3]));
            f32x2 sA = __builtin_elementwise_fma(g1, sp2(w2f.y), g0 * w2f.x);
            f32x2 sB = __builtin_elementwise_fma(g3, sp2(w2f.w), g2 * w2f.z);
            f32x2 s = sA + sB;
            s.x += __shfl_xor(s.x, 16);
            s.y += __shfl_xor(s.y, 16);
            s.x += __shfl_xor(s.x, 32);
            s.y += __shfl_xor(s.y, 32);
            if (lane < 16) part2[w][jt * 16 + lane] = s;
            Kh0 = nKh0; Km0 = nKm0; Kh1 = nKh1; Km1 = nKm1;
        }
    }
    __syncthreads();

    // ---- scores (packed pair)
    f32x2 score = ((part2[0][t] + part2[1][t]) + (part2[2][t] + part2[3][t]) + b2v) * 0.125f;

    // ---- dual lockstep 256-wide bitonic sort (packed compare-exchange);
    //      sorted[192] = 64th largest.
    f32x2 sv = score;
    #pragma unroll
    for (int k = 2; k <= 256; k <<= 1) {
        #pragma unroll
        for (int j = k >> 1; j >= 1; j >>= 1) {
            f32x2 pv;
            if (j >= 64) {
                sbuf2[t] = sv;
                __syncthreads();
                pv = sbuf2[t ^ j];
                __syncthreads();
            } else {
                pv.x = __shfl_xor(sv.x, j);
                pv.y = __shfl_xor(sv.y, j);
            }
            bool keepMin = (((t & j) == 0) == ((t & k) == 0));
            f32x2 mn = __builtin_elementwise_min(sv, pv);
            f32x2 mx = __builtin_elementwise_max(sv, pv);
            sv = keepMin ? mn : mx;
        }
    }
    if (t == 192) thr_s2  = sv;
    if (t == 255) smax_s2 = sv;
    __syncthreads();

    // ---- softmax numerator + denominator (packed)
    float p0 = (score.x >= thr_s2.x) ? __expf(score.x - smax_s2.x) : 0.0f;
    float p1 = (score.y >= thr_s2.y) ? __expf(score.y - smax_s2.y) : 0.0f;
    sc2[t] = mk2(p0, p1);
    f32x2 ps = mk2(p0, p1);
    #pragma unroll
    for (int mask = 1; mask < 64; mask <<= 1) {
        ps.x += __shfl_xor(ps.x, mask);
        ps.y += __shfl_xor(ps.y, mask);
    }
    if (lane == 0) red2_s[w] = ps;
    __syncthreads();
    f32x2 den = (red2_s[0] + red2_s[1]) + (red2_s[2] + red2_s[3]);
    f32x2 invp = mk2(1.0f / den.x, 1.0f / den.y);

    // ---- attn @ V: packed accumulate, x2 unroll (8 V-loads in flight)
    const int d = t & 63, g = t >> 6;
    const float* vb = v + bh * 256 * 64;
    f32x2 av = mk2(0.f, 0.f), avb = mk2(0.f, 0.f);
    for (int j8 = 0; j8 < 8; j8++) {
        int jj = g * 64 + j8 * 8;
        f32x2 pp0 = sc2[jj + 0];
        f32x2 pp1 = sc2[jj + 1];
        f32x2 pp2 = sc2[jj + 2];
        f32x2 pp3 = sc2[jj + 3];
        f32x2 pp4 = sc2[jj + 4];
        f32x2 pp5 = sc2[jj + 5];
        f32x2 pp6 = sc2[jj + 6];
        f32x2 pp7 = sc2[jj + 7];
        float v0 = vb[(jj + 0) * 64 + d];
        float v1 = vb[(jj + 1) * 64 + d];
        float v2 = vb[(jj + 2) * 64 + d];
        float v3 = vb[(jj + 3) * 64 + d];
        float v4 = vb[(jj + 4) * 64 + d];
        float v5 = vb[(jj + 5) * 64 + d];
        float v6 = vb[(jj + 6) * 64 + d];
        float v7 = vb[(jj + 7) * 64 + d];
        av  = __builtin_elementwise_fma(pp0, sp2(v0), av);
        avb = __builtin_elementwise_fma(pp4, sp2(v4), avb);
        av  = __builtin_elementwise_fma(pp1, sp2(v1), av);
        avb = __builtin_elementwise_fma(pp5, sp2(v5), avb);
        av  = __builtin_elementwise_fma(pp2, sp2(v2), av);
        avb = __builtin_elementwise_fma(pp6, sp2(v6), avb);
        av  = __builtin_elementwise_fma(pp3, sp2(v3), av);
        avb = __builtin_elementwise_fma(pp7, sp2(v7), avb);
    }
    red_s[g][d] = av + avb;
    __syncthreads();

    // ---- output: (B,H,C,D)->(B,C,DM) row, written as dual-split frag-major
    if (t < 128) {
        int i01 = t >> 6, dd = t & 63;
        f32x2 osum = (red_s[0][dd] + red_s[1][dd]) + (red_s[2][dd] + red_s[3][dd]);
        float o = (i01 ? osum.y : osum.x) * (i01 ? invp.y : invp.x);
        int b = bh >> 3, h = bh & 7;
        int row = b * 256 + i2 * 2 + i01;
        int n = h * 64 + dd;
        int dst = (((row >> 4) * 16 + (n >> 5)) * 64 + ((n >> 3) & 3) * 16 + (row & 15)) * 8 + (n & 7);
        fp16 hh, mm;
        split2(o, hh, mm);
        oh[dst] = hh; om[dst] = mm;
    }
}

// ---------------------------------------------------------------------------
extern "C" void kernel_launch(void* const* d_in, const int* in_sizes, int n_in,
                              void* d_out, int out_size, void* d_ws, size_t ws_size,
                              hipStream_t stream) {
    const float* x  = (const float*)d_in[0];
    const float* Wq = (const float*)d_in[1];
    const float* bq = (const float*)d_in[2];
    const float* Wk = (const float*)d_in[3];
    const float* bk = (const float*)d_in[4];
    const float* Wv = (const float*)d_in[5];
    const float* bv = (const float*)d_in[6];
    const float* w1 = (const float*)d_in[7];
    const float* b1 = (const float*)d_in[8];
    const float* w2 = (const float*)d_in[9];
    const float* b2 = (const float*)d_in[10];
    const float* Wo = (const float*)d_in[11];
    const float* bo = (const float*)d_in[12];
    float* out = (float*)d_out;

    const int NE = 262144;   // 512*512
    float* qb  = (float*)d_ws;          // q (b,h,c,d) fp32
    float* vb  = qb + NE;               // v (b,h,c,d) fp32
    fp16* base = (fp16*)(vb + NE);
    fp16* khi  = base;            fp16* kmid = khi + NE;
    fp16* xs   = kmid + NE;       // hi/mid duals follow (2*NE each)
    fp16* wqs  = xs  + 2 * NE;
    fp16* wks  = wqs + 2 * NE;
    fp16* wvs  = wks + 2 * NE;
    fp16* wos  = wvs + 2 * NE;
    fp16* oas  = wos + 2 * NE;

    // 1) split x, Wq, Wk, Wv, Wo into frag-major fp16 duals
    {
        SplitArgs S;
        const float* srcs[5] = {x, Wq, Wk, Wv, Wo};
        fp16* dsts[5] = {xs, wqs, wks, wvs, wos};
        for (int z = 0; z < 5; z++) {
            S.src[z] = srcs[z];
            S.h[z] = dsts[z]; S.m[z] = dsts[z] + NE;
        }
        split2_512_kernel<<<dim3(256, 1, 5), 256, 0, stream>>>(S);
    }
    // 2) QKV projections; K written directly as dual-split frag-major
    {
        MM2Args M;
        M.Ah = xs; M.Am = xs + NE;
        M.Wh[0] = wqs; M.Wm[0] = wqs + NE;
        M.Wh[1] = wks; M.Wm[1] = wks + NE;
        M.Wh[2] = wvs; M.Wm[2] = wvs + NE;
        M.bias[0] = bq; M.bias[1] = bk; M.bias[2] = bv;
        M.outf[0] = qb; M.outf[1] = nullptr; M.outf[2] = vb;
        M.kh = khi; M.km = kmid;
        M.mode[0] = 1; M.mode[1] = 2; M.mode[2] = 1;
        mm_mfma_kernel<<<dim3(32, 32, 3), 64, 0, stream>>>(M);
    }
    // 3) fused second-order scores + top-64 + softmax + attn@V (+ dual out)
    fused_mfma_attn_kernel<<<dim3(128, 16), 256, 0, stream>>>(
        qb, vb, khi, kmid, w1, b1, w2, b2,
        oas, oas + NE);
    // 4) output projection
    {
        MM2Args M;
        M.Ah = oas; M.Am = oas + NE;
        M.Wh[0] = wos; M.Wm[0] = wos + NE;
        M.Wh[1] = wos; M.Wm[1] = wos;
        M.Wh[2] = wos; M.Wm[2] = wos;
        M.bias[0] = bo; M.bias[1] = bo; M.bias[2] = bo;
        M.outf[0] = out; M.outf[1] = out; M.outf[2] = out;
        M.kh = khi; M.km = kmid;
        M.mode[0] = 0; M.mode[1] = 0; M.mode[2] = 0;
        mm_mfma_kernel<<<dim3(32, 32, 1), 64, 0, stream>>>(M);
    }
}

// Round 8
// 170.071 us; speedup vs baseline: 1.1609x; 1.0186x over previous
//
#include <hip/hip_runtime.h>
#include <math.h>

// Problem constants: B=2, C=256, DM=512, H=8, D=64, SPARSE_K=64
typedef _Float16 fp16;
typedef __attribute__((ext_vector_type(4))) _Float16 f16x4;
typedef __attribute__((ext_vector_type(8))) _Float16 f16x8;
typedef __attribute__((ext_vector_type(4))) float floatx4;
typedef __attribute__((ext_vector_type(2))) float f32x2;

__device__ __forceinline__ f32x2 mk2(float a, float b) { f32x2 r; r.x = a; r.y = b; return r; }
__device__ __forceinline__ f32x2 sp2(float a) { f32x2 r; r.x = a; r.y = a; return r; }

// ---------------------------------------------------------------------------
// Packed-pair gelu (R1/R7-proven v_pk_fma_f32 lowering): 6-term Taylor erf on
// |t|<=0.5 (abs err <= 1.5e-8), erff fallback for rare outliers.
// ---------------------------------------------------------------------------
__device__ __forceinline__ f32x2 gelu2(f32x2 x) {
    f32x2 tt = x * 0.70710678118654752440f;
    f32x2 s  = tt * tt;
    f32x2 p  = __builtin_elementwise_fma(s, sp2(-8.548327023450852e-4f), sp2(5.223977625442188e-3f));
    p = __builtin_elementwise_fma(s, p, sp2(-2.6866170645131252e-2f));
    p = __builtin_elementwise_fma(s, p, sp2(0.11283791670955126f));
    p = __builtin_elementwise_fma(s, p, sp2(-0.3761263890318375f));
    p = __builtin_elementwise_fma(s, p, sp2(1.1283791670955126f));
    f32x2 e = tt * p;
    if (__builtin_expect(fabsf(tt.x) > 0.5f, 0)) e.x = erff(tt.x);
    if (__builtin_expect(fabsf(tt.y) > 0.5f, 0)) e.y = erff(tt.y);
    f32x2 hx = x * 0.5f;
    return __builtin_elementwise_fma(hx, e, hx);   // 0.5x + 0.5x*e
}

// ---------------------------------------------------------------------------
// fp16 DUAL split: h = fp16(x), m = fp16(x - h). ~22 mantissa bits; fp16*fp16
// products are EXACT in the fp32 MFMA accumulator (R5-verified, ~2^-22 rel).
// ---------------------------------------------------------------------------
__device__ __forceinline__ void split2(float a, fp16& h, fp16& m) {
    h = (fp16)a;
    m = (fp16)(a - (float)h);
}

// ---------------------------------------------------------------------------
// Dual-split into MFMA frag-major order for [512][512] matrices; 5 matrices
// batched via blockIdx.z. (row,k) -> ((rt*16+ks)*64 + q4*16 + rm)*8 + u.
// ---------------------------------------------------------------------------
struct SplitArgs {
    const float* src[5];
    fp16* h[5]; fp16* m[5];
};

__global__ __launch_bounds__(256) void split2_512_kernel(SplitArgs S) {
    int z = blockIdx.z;
    const float* src = S.src[z];
    fp16* dh = S.h[z]; fp16* dm = S.m[z];
    int t = blockIdx.x * 256 + threadIdx.x;
    int row = t >> 7, kq = (t & 127) * 4;
    int rt = row >> 4, rm = row & 15;
    int ks = kq >> 5, q4 = (kq >> 3) & 3, u0 = kq & 7;
    int dst = ((rt * 16 + ks) * 64 + q4 * 16 + rm) * 8 + u0;
    float4 vv = *(const float4*)&src[row * 512 + kq];
    float a4[4] = {vv.x, vv.y, vv.z, vv.w};
    f16x4 h, m;
    #pragma unroll
    for (int u = 0; u < 4; u++) {
        fp16 hh, mm;
        split2(a4[u], hh, mm);
        h[u] = hh; m[u] = mm;
    }
    *(f16x4*)&dh[dst] = h;
    *(f16x4*)&dm[dst] = m;
}

// ---------------------------------------------------------------------------
// C = A @ W^T + bias via dual-split fp16 MFMA (R5-proven). One wave per block
// computing a 16x16 tile; grid (32, 32, nz). 4 MFMAs per k-step in two
// independent 2-chains. mode 0: fp32 [m*512+n]; mode 1: heads fp32 (b,h,c,d);
// mode 2: K written directly as frag-major dual-split.
// ---------------------------------------------------------------------------
struct MM2Args {
    const fp16 *Ah, *Am;
    const fp16 *Wh[3], *Wm[3];
    const float* bias[3];
    float* outf[3];
    fp16 *kh, *km;
    int mode[3];
};

__global__ __launch_bounds__(64) void mm_mfma_kernel(MM2Args A) {
    const int z = blockIdx.z;
    const fp16* Wh = A.Wh[z]; const fp16* Wm = A.Wm[z];
    const float* bias = A.bias[z];
    const int lane = threadIdx.x;
    const int m16 = lane & 15, q4 = lane >> 4;
    const int mt = blockIdx.y, bx = blockIdx.x;

    floatx4 acc0, acc1;
    {
        float bv = bias[bx * 16 + m16];
        acc0[0] = bv; acc0[1] = bv; acc0[2] = bv; acc0[3] = bv;
        acc1[0] = 0.f; acc1[1] = 0.f; acc1[2] = 0.f; acc1[3] = 0.f;
    }

    #pragma unroll 4
    for (int ks = 0; ks < 16; ks++) {
        int sa = ((mt * 16 + ks) * 64 + lane) * 8;
        f16x8 ah = *(const f16x8*)&A.Ah[sa];
        f16x8 am = *(const f16x8*)&A.Am[sa];
        int sw = ((bx * 16 + ks) * 64 + lane) * 8;
        f16x8 wh = *(const f16x8*)&Wh[sw];
        f16x8 wm = *(const f16x8*)&Wm[sw];
        acc0 = __builtin_amdgcn_mfma_f32_16x16x32_f16(ah, wh, acc0, 0, 0, 0);
        acc1 = __builtin_amdgcn_mfma_f32_16x16x32_f16(ah, wm, acc1, 0, 0, 0);
        acc0 = __builtin_amdgcn_mfma_f32_16x16x32_f16(am, wh, acc0, 0, 0, 0);
        acc1 = __builtin_amdgcn_mfma_f32_16x16x32_f16(am, wm, acc1, 0, 0, 0);
    }
    floatx4 acc = acc0 + acc1;

    const int mode = A.mode[z];
    const int n = bx * 16 + m16;
    #pragma unroll
    for (int r = 0; r < 4; r++) {
        int m = mt * 16 + q4 * 4 + r;
        float val = acc[r];
        if (mode == 0) {
            A.outf[z][m * 512 + n] = val;
        } else if (mode == 1) {
            A.outf[z][(((m >> 8) * 8 + (n >> 6)) * 256 + (m & 255)) * 64 + (n & 63)] = val;
        } else {
            int krow = ((m >> 8) * 8 + (n >> 6)) * 256 + (m & 255);
            int d = n & 63;
            int dst = (((krow >> 4) * 2 + (d >> 5)) * 64 + ((d >> 3) & 3) * 16 + (krow & 15)) * 8 + (d & 7);
            fp16 h, mm;
            split2(val, h, mm);
            A.kh[dst] = h; A.km[dst] = mm;
        }
    }
}

// ---------------------------------------------------------------------------
// Fused per-(bh, i-quad). R8: NI=2 -> NI=4 amortization.
// Timing model (R7 counters): T = (blocks_per_CU / 3 resident) x L_block,
// L ~= 30.6us of which ~80% is stall (shfl chains, load-use latency,
// barriers) — invariant to per-block work (R1/R5/R7 all flat). NI=4 halves
// blocks_per_CU (8->4) while L grows sub-2x because the stall phases are
// query-invariant: K loads/block UNCHANGED, sort chain+barriers UNCHANGED
// (4 lockstep values), V loads shared x4, w1 loads hoisted (query-invariant).
// Registers: A 64 + K 32 + accs 16 + qpbr 16 + misc ~25 ~= 155 <= 170 cap
// from __launch_bounds__(256,3) -> 3 waves/SIMD retained.
// ---------------------------------------------------------------------------
__global__ __launch_bounds__(256, 3) void fused_mfma_attn_kernel(
    const float* __restrict__ q, const float* __restrict__ v,
    const fp16* __restrict__ khi, const fp16* __restrict__ kmid,
    const float* __restrict__ w1, const float* __restrict__ b1,
    const float* __restrict__ w2, const float* __restrict__ b2,
    fp16* __restrict__ oh, fp16* __restrict__ om)
{
    const int i4 = blockIdx.x;     // query quad: i = 4*i4 + i01
    const int bh = blockIdx.y;
    const int t  = threadIdx.x;
    const int lane = t & 63, w = t >> 6;
    const int m16 = lane & 15, q4 = lane >> 4;

    __shared__ f32x2 part2[2][4][256];  // [pair][wave][j] score partials
    __shared__ f32x2 sc2[2][256];       // softmax probabilities, 2 pairs
    __shared__ float qpb_s[4][64];
    __shared__ f32x2 sbuf2[2][256];     // bitonic cross-wave exchange
    __shared__ f32x2 red_s[2][4][64];   // attn@V partials
    __shared__ f32x2 red2_s[2][4];
    __shared__ f32x2 thr_s2[2], smax_s2[2];

    const int f = w * 16 + m16;         // this lane's f (A-operand M index)
    const float* w1row = w1 + f * 192;

    // ---- build A_i fragments for 4 queries + qpb; w1 loads hoisted (they
    //      are query-invariant — previously loaded once per query)
    f16x8 Ah[4][2], Am[4][2];
    float qa[4] = {0.f, 0.f, 0.f, 0.f};
    const float* qbase = q + (bh * 256 + i4 * 4) * 64;
    #pragma unroll
    for (int ks = 0; ks < 2; ks++) {
        #pragma unroll
        for (int u = 0; u < 2; u++) {
            int e = ks * 32 + q4 * 8 + u * 4;
            float4 wa = *(const float4*)&w1row[e];
            float4 wb = *(const float4*)&w1row[64 + e];
            float4 wc = *(const float4*)&w1row[128 + e];
            #pragma unroll
            for (int i01 = 0; i01 < 4; i01++) {
                float4 qv = *(const float4*)&qbase[i01 * 64 + e];
                qa[i01] += wa.x * qv.x + wa.y * qv.y + wa.z * qv.z + wa.w * qv.w;
                float av[4];
                av[0] = fmaf(wc.x, qv.x, wb.x);
                av[1] = fmaf(wc.y, qv.y, wb.y);
                av[2] = fmaf(wc.z, qv.z, wb.z);
                av[3] = fmaf(wc.w, qv.w, wb.w);
                #pragma unroll
                for (int uu = 0; uu < 4; uu++) {
                    fp16 h, m;
                    split2(av[uu], h, m);
                    Ah[i01][ks][u * 4 + uu] = h;
                    Am[i01][ks][u * 4 + uu] = m;
                }
            }
        }
    }
    #pragma unroll
    for (int i01 = 0; i01 < 4; i01++) {
        float qaa = qa[i01];
        qaa += __shfl_xor(qaa, 16);
        qaa += __shfl_xor(qaa, 32);
        if (lane < 16) qpb_s[i01][w * 16 + lane] = qaa + b1[w * 16 + lane];
    }
    __syncthreads();

    floatx4 qpbr[4];
    #pragma unroll
    for (int i01 = 0; i01 < 4; i01++)
        qpbr[i01] = *(const floatx4*)&qpb_s[i01][w * 16 + q4 * 4];
    const float4 w2f = *(const float4*)&w2[w * 16 + q4 * 4];
    const float b2v = b2[0];

    // ---- main loop: prefetched K (shared by all 4 queries), 2 pairs of
    //      4 interleaved MFMA chains, packed epilogues
    {
        int base = ((bh * 16) * 2 * 64 + lane) * 8;
        f16x8 Kh0 = *(const f16x8*)&khi [base];
        f16x8 Km0 = *(const f16x8*)&kmid[base];
        f16x8 Kh1 = *(const f16x8*)&khi [base + 512];
        f16x8 Km1 = *(const f16x8*)&kmid[base + 512];
        #pragma unroll 1
        for (int jt = 0; jt < 16; jt++) {
            f16x8 nKh0, nKm0, nKh1, nKm1;
            if (jt < 15) {
                int nb = ((bh * 16 + jt + 1) * 2 * 64 + lane) * 8;
                nKh0 = *(const f16x8*)&khi [nb];
                nKm0 = *(const f16x8*)&kmid[nb];
                nKh1 = *(const f16x8*)&khi [nb + 512];
                nKm1 = *(const f16x8*)&kmid[nb + 512];
            }
            #pragma unroll
            for (int p = 0; p < 2; p++) {
                const int ia = 2 * p, ib = 2 * p + 1;
                floatx4 a0 = qpbr[ia], a1 = qpbr[ib];
                floatx4 b0, b1v_;
                b0[0] = 0.f; b0[1] = 0.f; b0[2] = 0.f; b0[3] = 0.f;
                b1v_ = b0;
                // 16 MFMAs as 4 independent 4-chains, round-robin issued
                a0   = __builtin_amdgcn_mfma_f32_16x16x32_f16(Ah[ia][0], Kh0, a0,   0, 0, 0);
                a1   = __builtin_amdgcn_mfma_f32_16x16x32_f16(Ah[ib][0], Kh0, a1,   0, 0, 0);
                b0   = __builtin_amdgcn_mfma_f32_16x16x32_f16(Ah[ia][0], Km0, b0,   0, 0, 0);
                b1v_ = __builtin_amdgcn_mfma_f32_16x16x32_f16(Ah[ib][0], Km0, b1v_, 0, 0, 0);
                a0   = __builtin_amdgcn_mfma_f32_16x16x32_f16(Am[ia][0], Kh0, a0,   0, 0, 0);
                a1   = __builtin_amdgcn_mfma_f32_16x16x32_f16(Am[ib][0], Kh0, a1,   0, 0, 0);
                b0   = __builtin_amdgcn_mfma_f32_16x16x32_f16(Am[ia][0], Km0, b0,   0, 0, 0);
                b1v_ = __builtin_amdgcn_mfma_f32_16x16x32_f16(Am[ib][0], Km0, b1v_, 0, 0, 0);
                a0   = __builtin_amdgcn_mfma_f32_16x16x32_f16(Ah[ia][1], Kh1, a0,   0, 0, 0);
                a1   = __builtin_amdgcn_mfma_f32_16x16x32_f16(Ah[ib][1], Kh1, a1,   0, 0, 0);
                b0   = __builtin_amdgcn_mfma_f32_16x16x32_f16(Ah[ia][1], Km1, b0,   0, 0, 0);
                b1v_ = __builtin_amdgcn_mfma_f32_16x16x32_f16(Ah[ib][1], Km1, b1v_, 0, 0, 0);
                a0   = __builtin_amdgcn_mfma_f32_16x16x32_f16(Am[ia][1], Kh1, a0,   0, 0, 0);
                a1   = __builtin_amdgcn_mfma_f32_16x16x32_f16(Am[ib][1], Kh1, a1,   0, 0, 0);
                b0   = __builtin_amdgcn_mfma_f32_16x16x32_f16(Am[ia][1], Km1, b0,   0, 0, 0);
                b1v_ = __builtin_amdgcn_mfma_f32_16x16x32_f16(Am[ib][1], Km1, b1v_, 0, 0, 0);
                a0 = a0 + b0; a1 = a1 + b1v_;
                // packed epilogue on (ia,ib) pair
                f32x2 g0 = gelu2(mk2(a0[0], a1[0]));
                f32x2 g1 = gelu2(mk2(a0[1], a1[1]));
                f32x2 g2 = gelu2(mk2(a0[2], a1[2]));
                f32x2 g3 = gelu2(mk2(a0[3], a1[3]));
                f32x2 sA = __builtin_elementwise_fma(g1, sp2(w2f.y), g0 * w2f.x);
                f32x2 sB = __builtin_elementwise_fma(g3, sp2(w2f.w), g2 * w2f.z);
                f32x2 s = sA + sB;
                s.x += __shfl_xor(s.x, 16);
                s.y += __shfl_xor(s.y, 16);
                s.x += __shfl_xor(s.x, 32);
                s.y += __shfl_xor(s.y, 32);
                if (lane < 16) part2[p][w][jt * 16 + lane] = s;
            }
            Kh0 = nKh0; Km0 = nKm0; Kh1 = nKh1; Km1 = nKm1;
        }
    }
    __syncthreads();

    // ---- scores (two packed pairs = 4 queries)
    f32x2 score0 = ((part2[0][0][t] + part2[0][1][t]) +
                    (part2[0][2][t] + part2[0][3][t]) + b2v) * 0.125f;
    f32x2 score1 = ((part2[1][0][t] + part2[1][1][t]) +
                    (part2[1][2][t] + part2[1][3][t]) + b2v) * 0.125f;

    // ---- quad lockstep 256-wide bitonic sort (same chain depth & barrier
    //      count as the old dual sort); sorted[192] = 64th largest.
    f32x2 sv0 = score0, sv1 = score1;
    #pragma unroll
    for (int k = 2; k <= 256; k <<= 1) {
        #pragma unroll
        for (int j = k >> 1; j >= 1; j >>= 1) {
            f32x2 pv0, pv1;
            if (j >= 64) {
                sbuf2[0][t] = sv0; sbuf2[1][t] = sv1;
                __syncthreads();
                pv0 = sbuf2[0][t ^ j]; pv1 = sbuf2[1][t ^ j];
                __syncthreads();
            } else {
                pv0.x = __shfl_xor(sv0.x, j);
                pv0.y = __shfl_xor(sv0.y, j);
                pv1.x = __shfl_xor(sv1.x, j);
                pv1.y = __shfl_xor(sv1.y, j);
            }
            bool keepMin = (((t & j) == 0) == ((t & k) == 0));
            f32x2 mn0 = __builtin_elementwise_min(sv0, pv0);
            f32x2 mx0 = __builtin_elementwise_max(sv0, pv0);
            f32x2 mn1 = __builtin_elementwise_min(sv1, pv1);
            f32x2 mx1 = __builtin_elementwise_max(sv1, pv1);
            sv0 = keepMin ? mn0 : mx0;
            sv1 = keepMin ? mn1 : mx1;
        }
    }
    if (t == 192) { thr_s2[0]  = sv0; thr_s2[1]  = sv1; }
    if (t == 255) { smax_s2[0] = sv0; smax_s2[1] = sv1; }
    __syncthreads();

    // ---- softmax numerator + denominator (two packed pairs)
    float p00 = (score0.x >= thr_s2[0].x) ? __expf(score0.x - smax_s2[0].x) : 0.0f;
    float p01 = (score0.y >= thr_s2[0].y) ? __expf(score0.y - smax_s2[0].y) : 0.0f;
    float p10 = (score1.x >= thr_s2[1].x) ? __expf(score1.x - smax_s2[1].x) : 0.0f;
    float p11 = (score1.y >= thr_s2[1].y) ? __expf(score1.y - smax_s2[1].y) : 0.0f;
    sc2[0][t] = mk2(p00, p01);
    sc2[1][t] = mk2(p10, p11);
    f32x2 ps0 = mk2(p00, p01), ps1 = mk2(p10, p11);
    #pragma unroll
    for (int mask = 1; mask < 64; mask <<= 1) {
        ps0.x += __shfl_xor(ps0.x, mask);
        ps0.y += __shfl_xor(ps0.y, mask);
        ps1.x += __shfl_xor(ps1.x, mask);
        ps1.y += __shfl_xor(ps1.y, mask);
    }
    if (lane == 0) { red2_s[0][w] = ps0; red2_s[1][w] = ps1; }
    __syncthreads();
    f32x2 den0 = (red2_s[0][0] + red2_s[0][1]) + (red2_s[0][2] + red2_s[0][3]);
    f32x2 den1 = (red2_s[1][0] + red2_s[1][1]) + (red2_s[1][2] + red2_s[1][3]);
    f32x2 invp0 = mk2(1.0f / den0.x, 1.0f / den0.y);
    f32x2 invp1 = mk2(1.0f / den1.x, 1.0f / den1.y);

    // ---- attn @ V: V loads shared across all 4 queries, x2 unroll
    const int d = t & 63, g = t >> 6;
    const float* vb = v + bh * 256 * 64;
    f32x2 av0 = mk2(0.f, 0.f), av1 = mk2(0.f, 0.f);
    f32x2 av0b = mk2(0.f, 0.f), av1b = mk2(0.f, 0.f);
    for (int j8 = 0; j8 < 8; j8++) {
        int jj = g * 64 + j8 * 8;
        float v0 = vb[(jj + 0) * 64 + d];
        float v1 = vb[(jj + 1) * 64 + d];
        float v2 = vb[(jj + 2) * 64 + d];
        float v3 = vb[(jj + 3) * 64 + d];
        float v4 = vb[(jj + 4) * 64 + d];
        float v5 = vb[(jj + 5) * 64 + d];
        float v6 = vb[(jj + 6) * 64 + d];
        float v7 = vb[(jj + 7) * 64 + d];
        av0  = __builtin_elementwise_fma(sc2[0][jj + 0], sp2(v0), av0);
        av1  = __builtin_elementwise_fma(sc2[1][jj + 0], sp2(v0), av1);
        av0b = __builtin_elementwise_fma(sc2[0][jj + 4], sp2(v4), av0b);
        av1b = __builtin_elementwise_fma(sc2[1][jj + 4], sp2(v4), av1b);
        av0  = __builtin_elementwise_fma(sc2[0][jj + 1], sp2(v1), av0);
        av1  = __builtin_elementwise_fma(sc2[1][jj + 1], sp2(v1), av1);
        av0b = __builtin_elementwise_fma(sc2[0][jj + 5], sp2(v5), av0b);
        av1b = __builtin_elementwise_fma(sc2[1][jj + 5], sp2(v5), av1b);
        av0  = __builtin_elementwise_fma(sc2[0][jj + 2], sp2(v2), av0);
        av1  = __builtin_elementwise_fma(sc2[1][jj + 2], sp2(v2), av1);
        av0b = __builtin_elementwise_fma(sc2[0][jj + 6], sp2(v6), av0b);
        av1b = __builtin_elementwise_fma(sc2[1][jj + 6], sp2(v6), av1b);
        av0  = __builtin_elementwise_fma(sc2[0][jj + 3], sp2(v3), av0);
        av1  = __builtin_elementwise_fma(sc2[1][jj + 3], sp2(v3), av1);
        av0b = __builtin_elementwise_fma(sc2[0][jj + 7], sp2(v7), av0b);
        av1b = __builtin_elementwise_fma(sc2[1][jj + 7], sp2(v7), av1b);
    }
    red_s[0][g][d] = av0 + av0b;
    red_s[1][g][d] = av1 + av1b;
    __syncthreads();

    // ---- output: all 256 threads write one (i01, dd) each
    {
        int i01 = t >> 6, dd = t & 63;
        int pr = i01 >> 1, comp = i01 & 1;
        f32x2 osum = (red_s[pr][0][dd] + red_s[pr][1][dd]) +
                     (red_s[pr][2][dd] + red_s[pr][3][dd]);
        f32x2 iv = pr ? invp1 : invp0;
        float o = (comp ? osum.y : osum.x) * (comp ? iv.y : iv.x);
        int b = bh >> 3, h = bh & 7;
        int row = b * 256 + i4 * 4 + i01;
        int n = h * 64 + dd;
        int dst = (((row >> 4) * 16 + (n >> 5)) * 64 + ((n >> 3) & 3) * 16 + (row & 15)) * 8 + (n & 7);
        fp16 hh, mm;
        split2(o, hh, mm);
        oh[dst] = hh; om[dst] = mm;
    }
}

// ---------------------------------------------------------------------------
extern "C" void kernel_launch(void* const* d_in, const int* in_sizes, int n_in,
                              void* d_out, int out_size, void* d_ws, size_t ws_size,
                              hipStream_t stream) {
    const float* x  = (const float*)d_in[0];
    const float* Wq = (const float*)d_in[1];
    const float* bq = (const float*)d_in[2];
    const float* Wk = (const float*)d_in[3];
    const float* bk = (const float*)d_in[4];
    const float* Wv = (const float*)d_in[5];
    const float* bv = (const float*)d_in[6];
    const float* w1 = (const float*)d_in[7];
    const float* b1 = (const float*)d_in[8];
    const float* w2 = (const float*)d_in[9];
    const float* b2 = (const float*)d_in[10];
    const float* Wo = (const float*)d_in[11];
    const float* bo = (const float*)d_in[12];
    float* out = (float*)d_out;

    const int NE = 262144;   // 512*512
    float* qb  = (float*)d_ws;          // q (b,h,c,d) fp32
    float* vb  = qb + NE;               // v (b,h,c,d) fp32
    fp16* base = (fp16*)(vb + NE);
    fp16* khi  = base;            fp16* kmid = khi + NE;
    fp16* xs   = kmid + NE;       // hi/mid duals follow (2*NE each)
    fp16* wqs  = xs  + 2 * NE;
    fp16* wks  = wqs + 2 * NE;
    fp16* wvs  = wks + 2 * NE;
    fp16* wos  = wvs + 2 * NE;
    fp16* oas  = wos + 2 * NE;

    // 1) split x, Wq, Wk, Wv, Wo into frag-major fp16 duals
    {
        SplitArgs S;
        const float* srcs[5] = {x, Wq, Wk, Wv, Wo};
        fp16* dsts[5] = {xs, wqs, wks, wvs, wos};
        for (int z = 0; z < 5; z++) {
            S.src[z] = srcs[z];
            S.h[z] = dsts[z]; S.m[z] = dsts[z] + NE;
        }
        split2_512_kernel<<<dim3(256, 1, 5), 256, 0, stream>>>(S);
    }
    // 2) QKV projections; K written directly as dual-split frag-major
    {
        MM2Args M;
        M.Ah = xs; M.Am = xs + NE;
        M.Wh[0] = wqs; M.Wm[0] = wqs + NE;
        M.Wh[1] = wks; M.Wm[1] = wks + NE;
        M.Wh[2] = wvs; M.Wm[2] = wvs + NE;
        M.bias[0] = bq; M.bias[1] = bk; M.bias[2] = bv;
        M.outf[0] = qb; M.outf[1] = nullptr; M.outf[2] = vb;
        M.kh = khi; M.km = kmid;
        M.mode[0] = 1; M.mode[1] = 2; M.mode[2] = 1;
        mm_mfma_kernel<<<dim3(32, 32, 3), 64, 0, stream>>>(M);
    }
    // 3) fused second-order scores + top-64 + softmax + attn@V (+ dual out)
    fused_mfma_attn_kernel<<<dim3(64, 16), 256, 0, stream>>>(
        qb, vb, khi, kmid, w1, b1, w2, b2,
        oas, oas + NE);
    // 4) output projection
    {
        MM2Args M;
        M.Ah = oas; M.Am = oas + NE;
        M.Wh[0] = wos; M.Wm[0] = wos + NE;
        M.Wh[1] = wos; M.Wm[1] = wos;
        M.Wh[2] = wos; M.Wm[2] = wos;
        M.bias[0] = bo; M.bias[1] = bo; M.bias[2] = bo;
        M.outf[0] = out; M.outf[1] = out; M.outf[2] = out;
        M.kh = khi; M.km = kmid;
        M.mode[0] = 0; M.mode[1] = 0; M.mode[2] = 0;
        mm_mfma_kernel<<<dim3(32, 32, 1), 64, 0, stream>>>(M);
    }
}

// Round 9
// 163.280 us; speedup vs baseline: 1.2092x; 1.0416x over previous
//
#include <hip/hip_runtime.h>
#include <math.h>

// Problem constants: B=2, C=256, DM=512, H=8, D=64, SPARSE_K=64
typedef _Float16 fp16;
typedef __attribute__((ext_vector_type(4))) _Float16 f16x4;
typedef __attribute__((ext_vector_type(8))) _Float16 f16x8;
typedef __attribute__((ext_vector_type(4))) float floatx4;
typedef __attribute__((ext_vector_type(2))) float f32x2;

__device__ __forceinline__ f32x2 mk2(float a, float b) { f32x2 r; r.x = a; r.y = b; return r; }
__device__ __forceinline__ f32x2 sp2(float a) { f32x2 r; r.x = a; r.y = a; return r; }

// ---------------------------------------------------------------------------
// Packed-pair gelu (R1/R7-proven v_pk_fma_f32 lowering): 6-term Taylor erf on
// |t|<=0.5 (abs err <= 1.5e-8), erff fallback for rare outliers.
// ---------------------------------------------------------------------------
__device__ __forceinline__ f32x2 gelu2(f32x2 x) {
    f32x2 tt = x * 0.70710678118654752440f;
    f32x2 s  = tt * tt;
    f32x2 p  = __builtin_elementwise_fma(s, sp2(-8.548327023450852e-4f), sp2(5.223977625442188e-3f));
    p = __builtin_elementwise_fma(s, p, sp2(-2.6866170645131252e-2f));
    p = __builtin_elementwise_fma(s, p, sp2(0.11283791670955126f));
    p = __builtin_elementwise_fma(s, p, sp2(-0.3761263890318375f));
    p = __builtin_elementwise_fma(s, p, sp2(1.1283791670955126f));
    f32x2 e = tt * p;
    if (__builtin_expect(fabsf(tt.x) > 0.5f, 0)) e.x = erff(tt.x);
    if (__builtin_expect(fabsf(tt.y) > 0.5f, 0)) e.y = erff(tt.y);
    f32x2 hx = x * 0.5f;
    return __builtin_elementwise_fma(hx, e, hx);   // 0.5x + 0.5x*e
}

// ---------------------------------------------------------------------------
// fp16 DUAL split: h = fp16(x), m = fp16(x - h). ~22 mantissa bits; fp16*fp16
// products are EXACT in the fp32 MFMA accumulator (R5-verified, ~2^-22 rel).
// ---------------------------------------------------------------------------
__device__ __forceinline__ void split2(float a, fp16& h, fp16& m) {
    h = (fp16)a;
    m = (fp16)(a - (float)h);
}

// ---------------------------------------------------------------------------
// Dual-split into MFMA frag-major order for [512][512] matrices; 5 matrices
// batched via blockIdx.z. (row,k) -> ((rt*16+ks)*64 + q4*16 + rm)*8 + u.
// ---------------------------------------------------------------------------
struct SplitArgs {
    const float* src[5];
    fp16* h[5]; fp16* m[5];
};

__global__ __launch_bounds__(256) void split2_512_kernel(SplitArgs S) {
    int z = blockIdx.z;
    const float* src = S.src[z];
    fp16* dh = S.h[z]; fp16* dm = S.m[z];
    int t = blockIdx.x * 256 + threadIdx.x;
    int row = t >> 7, kq = (t & 127) * 4;
    int rt = row >> 4, rm = row & 15;
    int ks = kq >> 5, q4 = (kq >> 3) & 3, u0 = kq & 7;
    int dst = ((rt * 16 + ks) * 64 + q4 * 16 + rm) * 8 + u0;
    float4 vv = *(const float4*)&src[row * 512 + kq];
    float a4[4] = {vv.x, vv.y, vv.z, vv.w};
    f16x4 h, m;
    #pragma unroll
    for (int u = 0; u < 4; u++) {
        fp16 hh, mm;
        split2(a4[u], hh, mm);
        h[u] = hh; m[u] = mm;
    }
    *(f16x4*)&dh[dst] = h;
    *(f16x4*)&dm[dst] = m;
}

// ---------------------------------------------------------------------------
// C = A @ W^T + bias via dual-split fp16 MFMA (R5-proven). One wave per block
// computing a 16x16 tile; grid (32, 32, nz). 4 MFMAs per k-step in two
// independent 2-chains. mode 0: fp32 [m*512+n]; mode 1: heads fp32 (b,h,c,d);
// mode 2: K written directly as frag-major dual-split.
// ---------------------------------------------------------------------------
struct MM2Args {
    const fp16 *Ah, *Am;
    const fp16 *Wh[3], *Wm[3];
    const float* bias[3];
    float* outf[3];
    fp16 *kh, *km;
    int mode[3];
};

__global__ __launch_bounds__(64) void mm_mfma_kernel(MM2Args A) {
    const int z = blockIdx.z;
    const fp16* Wh = A.Wh[z]; const fp16* Wm = A.Wm[z];
    const float* bias = A.bias[z];
    const int lane = threadIdx.x;
    const int m16 = lane & 15, q4 = lane >> 4;
    const int mt = blockIdx.y, bx = blockIdx.x;

    floatx4 acc0, acc1;
    {
        float bv = bias[bx * 16 + m16];
        acc0[0] = bv; acc0[1] = bv; acc0[2] = bv; acc0[3] = bv;
        acc1[0] = 0.f; acc1[1] = 0.f; acc1[2] = 0.f; acc1[3] = 0.f;
    }

    #pragma unroll 4
    for (int ks = 0; ks < 16; ks++) {
        int sa = ((mt * 16 + ks) * 64 + lane) * 8;
        f16x8 ah = *(const f16x8*)&A.Ah[sa];
        f16x8 am = *(const f16x8*)&A.Am[sa];
        int sw = ((bx * 16 + ks) * 64 + lane) * 8;
        f16x8 wh = *(const f16x8*)&Wh[sw];
        f16x8 wm = *(const f16x8*)&Wm[sw];
        acc0 = __builtin_amdgcn_mfma_f32_16x16x32_f16(ah, wh, acc0, 0, 0, 0);
        acc1 = __builtin_amdgcn_mfma_f32_16x16x32_f16(ah, wm, acc1, 0, 0, 0);
        acc0 = __builtin_amdgcn_mfma_f32_16x16x32_f16(am, wh, acc0, 0, 0, 0);
        acc1 = __builtin_amdgcn_mfma_f32_16x16x32_f16(am, wm, acc1, 0, 0, 0);
    }
    floatx4 acc = acc0 + acc1;

    const int mode = A.mode[z];
    const int n = bx * 16 + m16;
    #pragma unroll
    for (int r = 0; r < 4; r++) {
        int m = mt * 16 + q4 * 4 + r;
        float val = acc[r];
        if (mode == 0) {
            A.outf[z][m * 512 + n] = val;
        } else if (mode == 1) {
            A.outf[z][(((m >> 8) * 8 + (n >> 6)) * 256 + (m & 255)) * 64 + (n & 63)] = val;
        } else {
            int krow = ((m >> 8) * 8 + (n >> 6)) * 256 + (m & 255);
            int d = n & 63;
            int dst = (((krow >> 4) * 2 + (d >> 5)) * 64 + ((d >> 3) & 3) * 16 + (krow & 15)) * 8 + (d & 7);
            fp16 h, mm;
            split2(val, h, mm);
            A.kh[dst] = h; A.km[dst] = mm;
        }
    }
}

// ---------------------------------------------------------------------------
// Fused per-(bh, i-quad). R9: NI=4 with 4-resident register diet.
// R8 post-mortem: NI=4 amortization WORKED (L grew only 1.5x for 2x work:
// 30.6 -> 46us) but regs >170 dropped residency to 2 blocks/CU, and with
// exactly 4 blocks/CU of work that quantizes to 2 sequential rounds: T=2L=92.
// The magic number is 4 resident (T = 1 x L ~= 46-60us). Diet to <=128 total:
//  - K prefetch registers dropped (-16): K slice per bh is ~64KB, L2-resident
//    and shared by 4 i4-blocks; the 2->4 waves/SIMD TLP jump replaces the
//    latency cover the prefetch provided.
//  - __launch_bounds__(256,4) caps allocation at the 128/4-wave boundary.
// Live set in hot loop: A 64 + K 16 + acc 8 + qpbr 16 + misc ~20 ~= 124.
// Spill check: FETCH_SIZE must stay ~9MB (R2's failure signature was 608MB).
// ---------------------------------------------------------------------------
__global__ __launch_bounds__(256, 4) void fused_mfma_attn_kernel(
    const float* __restrict__ q, const float* __restrict__ v,
    const fp16* __restrict__ khi, const fp16* __restrict__ kmid,
    const float* __restrict__ w1, const float* __restrict__ b1,
    const float* __restrict__ w2, const float* __restrict__ b2,
    fp16* __restrict__ oh, fp16* __restrict__ om)
{
    const int i4 = blockIdx.x;     // query quad: i = 4*i4 + i01
    const int bh = blockIdx.y;
    const int t  = threadIdx.x;
    const int lane = t & 63, w = t >> 6;
    const int m16 = lane & 15, q4 = lane >> 4;

    __shared__ f32x2 part2[2][4][256];  // [pair][wave][j] score partials
    __shared__ f32x2 sc2[2][256];       // softmax probabilities, 2 pairs
    __shared__ float qpb_s[4][64];
    __shared__ f32x2 sbuf2[2][256];     // bitonic cross-wave exchange
    __shared__ f32x2 red_s[2][4][64];   // attn@V partials
    __shared__ f32x2 red2_s[2][4];
    __shared__ f32x2 thr_s2[2], smax_s2[2];

    const int f = w * 16 + m16;         // this lane's f (A-operand M index)
    const float* w1row = w1 + f * 192;

    // ---- build A_i fragments for 4 queries + qpb; w1 loads hoisted
    f16x8 Ah[4][2], Am[4][2];
    float qa[4] = {0.f, 0.f, 0.f, 0.f};
    const float* qbase = q + (bh * 256 + i4 * 4) * 64;
    #pragma unroll
    for (int ks = 0; ks < 2; ks++) {
        #pragma unroll
        for (int u = 0; u < 2; u++) {
            int e = ks * 32 + q4 * 8 + u * 4;
            float4 wa = *(const float4*)&w1row[e];
            float4 wb = *(const float4*)&w1row[64 + e];
            float4 wc = *(const float4*)&w1row[128 + e];
            #pragma unroll
            for (int i01 = 0; i01 < 4; i01++) {
                float4 qv = *(const float4*)&qbase[i01 * 64 + e];
                qa[i01] += wa.x * qv.x + wa.y * qv.y + wa.z * qv.z + wa.w * qv.w;
                float av[4];
                av[0] = fmaf(wc.x, qv.x, wb.x);
                av[1] = fmaf(wc.y, qv.y, wb.y);
                av[2] = fmaf(wc.z, qv.z, wb.z);
                av[3] = fmaf(wc.w, qv.w, wb.w);
                #pragma unroll
                for (int uu = 0; uu < 4; uu++) {
                    fp16 h, m;
                    split2(av[uu], h, m);
                    Ah[i01][ks][u * 4 + uu] = h;
                    Am[i01][ks][u * 4 + uu] = m;
                }
            }
        }
    }
    #pragma unroll
    for (int i01 = 0; i01 < 4; i01++) {
        float qaa = qa[i01];
        qaa += __shfl_xor(qaa, 16);
        qaa += __shfl_xor(qaa, 32);
        if (lane < 16) qpb_s[i01][w * 16 + lane] = qaa + b1[w * 16 + lane];
    }
    __syncthreads();

    floatx4 qpbr[4];
    #pragma unroll
    for (int i01 = 0; i01 < 4; i01++)
        qpbr[i01] = *(const floatx4*)&qpb_s[i01][w * 16 + q4 * 4];
    const float4 w2f = *(const float4*)&w2[w * 16 + q4 * 4];
    const float b2v = b2[0];

    // ---- main loop: K loaded in-loop (no prefetch regs — TLP covers it),
    //      2 pairs of 4 interleaved MFMA chains, packed epilogues
    #pragma unroll 1
    for (int jt = 0; jt < 16; jt++) {
        int base = ((bh * 16 + jt) * 2 * 64 + lane) * 8;
        f16x8 Kh0 = *(const f16x8*)&khi [base];
        f16x8 Km0 = *(const f16x8*)&kmid[base];
        f16x8 Kh1 = *(const f16x8*)&khi [base + 512];
        f16x8 Km1 = *(const f16x8*)&kmid[base + 512];
        #pragma unroll
        for (int p = 0; p < 2; p++) {
            const int ia = 2 * p, ib = 2 * p + 1;
            floatx4 a0 = qpbr[ia], a1 = qpbr[ib];
            floatx4 b0, b1v_;
            b0[0] = 0.f; b0[1] = 0.f; b0[2] = 0.f; b0[3] = 0.f;
            b1v_ = b0;
            // 16 MFMAs as 4 independent 4-chains, round-robin issued
            a0   = __builtin_amdgcn_mfma_f32_16x16x32_f16(Ah[ia][0], Kh0, a0,   0, 0, 0);
            a1   = __builtin_amdgcn_mfma_f32_16x16x32_f16(Ah[ib][0], Kh0, a1,   0, 0, 0);
            b0   = __builtin_amdgcn_mfma_f32_16x16x32_f16(Ah[ia][0], Km0, b0,   0, 0, 0);
            b1v_ = __builtin_amdgcn_mfma_f32_16x16x32_f16(Ah[ib][0], Km0, b1v_, 0, 0, 0);
            a0   = __builtin_amdgcn_mfma_f32_16x16x32_f16(Am[ia][0], Kh0, a0,   0, 0, 0);
            a1   = __builtin_amdgcn_mfma_f32_16x16x32_f16(Am[ib][0], Kh0, a1,   0, 0, 0);
            b0   = __builtin_amdgcn_mfma_f32_16x16x32_f16(Am[ia][0], Km0, b0,   0, 0, 0);
            b1v_ = __builtin_amdgcn_mfma_f32_16x16x32_f16(Am[ib][0], Km0, b1v_, 0, 0, 0);
            a0   = __builtin_amdgcn_mfma_f32_16x16x32_f16(Ah[ia][1], Kh1, a0,   0, 0, 0);
            a1   = __builtin_amdgcn_mfma_f32_16x16x32_f16(Ah[ib][1], Kh1, a1,   0, 0, 0);
            b0   = __builtin_amdgcn_mfma_f32_16x16x32_f16(Ah[ia][1], Km1, b0,   0, 0, 0);
            b1v_ = __builtin_amdgcn_mfma_f32_16x16x32_f16(Ah[ib][1], Km1, b1v_, 0, 0, 0);
            a0   = __builtin_amdgcn_mfma_f32_16x16x32_f16(Am[ia][1], Kh1, a0,   0, 0, 0);
            a1   = __builtin_amdgcn_mfma_f32_16x16x32_f16(Am[ib][1], Kh1, a1,   0, 0, 0);
            b0   = __builtin_amdgcn_mfma_f32_16x16x32_f16(Am[ia][1], Km1, b0,   0, 0, 0);
            b1v_ = __builtin_amdgcn_mfma_f32_16x16x32_f16(Am[ib][1], Km1, b1v_, 0, 0, 0);
            a0 = a0 + b0; a1 = a1 + b1v_;
            // packed epilogue on (ia,ib) pair
            f32x2 g0 = gelu2(mk2(a0[0], a1[0]));
            f32x2 g1 = gelu2(mk2(a0[1], a1[1]));
            f32x2 g2 = gelu2(mk2(a0[2], a1[2]));
            f32x2 g3 = gelu2(mk2(a0[3], a1[3]));
            f32x2 sA = __builtin_elementwise_fma(g1, sp2(w2f.y), g0 * w2f.x);
            f32x2 sB = __builtin_elementwise_fma(g3, sp2(w2f.w), g2 * w2f.z);
            f32x2 s = sA + sB;
            s.x += __shfl_xor(s.x, 16);
            s.y += __shfl_xor(s.y, 16);
            s.x += __shfl_xor(s.x, 32);
            s.y += __shfl_xor(s.y, 32);
            if (lane < 16) part2[p][w][jt * 16 + lane] = s;
        }
    }
    __syncthreads();

    // ---- scores (two packed pairs = 4 queries)
    f32x2 score0 = ((part2[0][0][t] + part2[0][1][t]) +
                    (part2[0][2][t] + part2[0][3][t]) + b2v) * 0.125f;
    f32x2 score1 = ((part2[1][0][t] + part2[1][1][t]) +
                    (part2[1][2][t] + part2[1][3][t]) + b2v) * 0.125f;

    // ---- quad lockstep 256-wide bitonic sort (same chain depth & barrier
    //      count as the old dual sort); sorted[192] = 64th largest.
    f32x2 sv0 = score0, sv1 = score1;
    #pragma unroll
    for (int k = 2; k <= 256; k <<= 1) {
        #pragma unroll
        for (int j = k >> 1; j >= 1; j >>= 1) {
            f32x2 pv0, pv1;
            if (j >= 64) {
                sbuf2[0][t] = sv0; sbuf2[1][t] = sv1;
                __syncthreads();
                pv0 = sbuf2[0][t ^ j]; pv1 = sbuf2[1][t ^ j];
                __syncthreads();
            } else {
                pv0.x = __shfl_xor(sv0.x, j);
                pv0.y = __shfl_xor(sv0.y, j);
                pv1.x = __shfl_xor(sv1.x, j);
                pv1.y = __shfl_xor(sv1.y, j);
            }
            bool keepMin = (((t & j) == 0) == ((t & k) == 0));
            f32x2 mn0 = __builtin_elementwise_min(sv0, pv0);
            f32x2 mx0 = __builtin_elementwise_max(sv0, pv0);
            f32x2 mn1 = __builtin_elementwise_min(sv1, pv1);
            f32x2 mx1 = __builtin_elementwise_max(sv1, pv1);
            sv0 = keepMin ? mn0 : mx0;
            sv1 = keepMin ? mn1 : mx1;
        }
    }
    if (t == 192) { thr_s2[0]  = sv0; thr_s2[1]  = sv1; }
    if (t == 255) { smax_s2[0] = sv0; smax_s2[1] = sv1; }
    __syncthreads();

    // ---- softmax numerator + denominator (two packed pairs)
    float p00 = (score0.x >= thr_s2[0].x) ? __expf(score0.x - smax_s2[0].x) : 0.0f;
    float p01 = (score0.y >= thr_s2[0].y) ? __expf(score0.y - smax_s2[0].y) : 0.0f;
    float p10 = (score1.x >= thr_s2[1].x) ? __expf(score1.x - smax_s2[1].x) : 0.0f;
    float p11 = (score1.y >= thr_s2[1].y) ? __expf(score1.y - smax_s2[1].y) : 0.0f;
    sc2[0][t] = mk2(p00, p01);
    sc2[1][t] = mk2(p10, p11);
    f32x2 ps0 = mk2(p00, p01), ps1 = mk2(p10, p11);
    #pragma unroll
    for (int mask = 1; mask < 64; mask <<= 1) {
        ps0.x += __shfl_xor(ps0.x, mask);
        ps0.y += __shfl_xor(ps0.y, mask);
        ps1.x += __shfl_xor(ps1.x, mask);
        ps1.y += __shfl_xor(ps1.y, mask);
    }
    if (lane == 0) { red2_s[0][w] = ps0; red2_s[1][w] = ps1; }
    __syncthreads();
    f32x2 den0 = (red2_s[0][0] + red2_s[0][1]) + (red2_s[0][2] + red2_s[0][3]);
    f32x2 den1 = (red2_s[1][0] + red2_s[1][1]) + (red2_s[1][2] + red2_s[1][3]);
    f32x2 invp0 = mk2(1.0f / den0.x, 1.0f / den0.y);
    f32x2 invp1 = mk2(1.0f / den1.x, 1.0f / den1.y);

    // ---- attn @ V: V loads shared across all 4 queries, x2 unroll
    const int d = t & 63, g = t >> 6;
    const float* vb = v + bh * 256 * 64;
    f32x2 av0 = mk2(0.f, 0.f), av1 = mk2(0.f, 0.f);
    f32x2 av0b = mk2(0.f, 0.f), av1b = mk2(0.f, 0.f);
    for (int j8 = 0; j8 < 8; j8++) {
        int jj = g * 64 + j8 * 8;
        float v0 = vb[(jj + 0) * 64 + d];
        float v1 = vb[(jj + 1) * 64 + d];
        float v2 = vb[(jj + 2) * 64 + d];
        float v3 = vb[(jj + 3) * 64 + d];
        float v4 = vb[(jj + 4) * 64 + d];
        float v5 = vb[(jj + 5) * 64 + d];
        float v6 = vb[(jj + 6) * 64 + d];
        float v7 = vb[(jj + 7) * 64 + d];
        av0  = __builtin_elementwise_fma(sc2[0][jj + 0], sp2(v0), av0);
        av1  = __builtin_elementwise_fma(sc2[1][jj + 0], sp2(v0), av1);
        av0b = __builtin_elementwise_fma(sc2[0][jj + 4], sp2(v4), av0b);
        av1b = __builtin_elementwise_fma(sc2[1][jj + 4], sp2(v4), av1b);
        av0  = __builtin_elementwise_fma(sc2[0][jj + 1], sp2(v1), av0);
        av1  = __builtin_elementwise_fma(sc2[1][jj + 1], sp2(v1), av1);
        av0b = __builtin_elementwise_fma(sc2[0][jj + 5], sp2(v5), av0b);
        av1b = __builtin_elementwise_fma(sc2[1][jj + 5], sp2(v5), av1b);
        av0  = __builtin_elementwise_fma(sc2[0][jj + 2], sp2(v2), av0);
        av1  = __builtin_elementwise_fma(sc2[1][jj + 2], sp2(v2), av1);
        av0b = __builtin_elementwise_fma(sc2[0][jj + 6], sp2(v6), av0b);
        av1b = __builtin_elementwise_fma(sc2[1][jj + 6], sp2(v6), av1b);
        av0  = __builtin_elementwise_fma(sc2[0][jj + 3], sp2(v3), av0);
        av1  = __builtin_elementwise_fma(sc2[1][jj + 3], sp2(v3), av1);
        av0b = __builtin_elementwise_fma(sc2[0][jj + 7], sp2(v7), av0b);
        av1b = __builtin_elementwise_fma(sc2[1][jj + 7], sp2(v7), av1b);
    }
    red_s[0][g][d] = av0 + av0b;
    red_s[1][g][d] = av1 + av1b;
    __syncthreads();

    // ---- output: all 256 threads write one (i01, dd) each
    {
        int i01 = t >> 6, dd = t & 63;
        int pr = i01 >> 1, comp = i01 & 1;
        f32x2 osum = (red_s[pr][0][dd] + red_s[pr][1][dd]) +
                     (red_s[pr][2][dd] + red_s[pr][3][dd]);
        f32x2 iv = pr ? invp1 : invp0;
        float o = (comp ? osum.y : osum.x) * (comp ? iv.y : iv.x);
        int b = bh >> 3, h = bh & 7;
        int row = b * 256 + i4 * 4 + i01;
        int n = h * 64 + dd;
        int dst = (((row >> 4) * 16 + (n >> 5)) * 64 + ((n >> 3) & 3) * 16 + (row & 15)) * 8 + (n & 7);
        fp16 hh, mm;
        split2(o, hh, mm);
        oh[dst] = hh; om[dst] = mm;
    }
}

// ---------------------------------------------------------------------------
extern "C" void kernel_launch(void* const* d_in, const int* in_sizes, int n_in,
                              void* d_out, int out_size, void* d_ws, size_t ws_size,
                              hipStream_t stream) {
    const float* x  = (const float*)d_in[0];
    const float* Wq = (const float*)d_in[1];
    const float* bq = (const float*)d_in[2];
    const float* Wk = (const float*)d_in[3];
    const float* bk = (const float*)d_in[4];
    const float* Wv = (const float*)d_in[5];
    const float* bv = (const float*)d_in[6];
    const float* w1 = (const float*)d_in[7];
    const float* b1 = (const float*)d_in[8];
    const float* w2 = (const float*)d_in[9];
    const float* b2 = (const float*)d_in[10];
    const float* Wo = (const float*)d_in[11];
    const float* bo = (const float*)d_in[12];
    float* out = (float*)d_out;

    const int NE = 262144;   // 512*512
    float* qb  = (float*)d_ws;          // q (b,h,c,d) fp32
    float* vb  = qb + NE;               // v (b,h,c,d) fp32
    fp16* base = (fp16*)(vb + NE);
    fp16* khi  = base;            fp16* kmid = khi + NE;
    fp16* xs   = kmid + NE;       // hi/mid duals follow (2*NE each)
    fp16* wqs  = xs  + 2 * NE;
    fp16* wks  = wqs + 2 * NE;
    fp16* wvs  = wks + 2 * NE;
    fp16* wos  = wvs + 2 * NE;
    fp16* oas  = wos + 2 * NE;

    // 1) split x, Wq, Wk, Wv, Wo into frag-major fp16 duals
    {
        SplitArgs S;
        const float* srcs[5] = {x, Wq, Wk, Wv, Wo};
        fp16* dsts[5] = {xs, wqs, wks, wvs, wos};
        for (int z = 0; z < 5; z++) {
            S.src[z] = srcs[z];
            S.h[z] = dsts[z]; S.m[z] = dsts[z] + NE;
        }
        split2_512_kernel<<<dim3(256, 1, 5), 256, 0, stream>>>(S);
    }
    // 2) QKV projections; K written directly as dual-split frag-major
    {
        MM2Args M;
        M.Ah = xs; M.Am = xs + NE;
        M.Wh[0] = wqs; M.Wm[0] = wqs + NE;
        M.Wh[1] = wks; M.Wm[1] = wks + NE;
        M.Wh[2] = wvs; M.Wm[2] = wvs + NE;
        M.bias[0] = bq; M.bias[1] = bk; M.bias[2] = bv;
        M.outf[0] = qb; M.outf[1] = nullptr; M.outf[2] = vb;
        M.kh = khi; M.km = kmid;
        M.mode[0] = 1; M.mode[1] = 2; M.mode[2] = 1;
        mm_mfma_kernel<<<dim3(32, 32, 3), 64, 0, stream>>>(M);
    }
    // 3) fused second-order scores + top-64 + softmax + attn@V (+ dual out)
    fused_mfma_attn_kernel<<<dim3(64, 16), 256, 0, stream>>>(
        qb, vb, khi, kmid, w1, b1, w2, b2,
        oas, oas + NE);
    // 4) output projection
    {
        MM2Args M;
        M.Ah = oas; M.Am = oas + NE;
        M.Wh[0] = wos; M.Wm[0] = wos + NE;
        M.Wh[1] = wos; M.Wm[1] = wos;
        M.Wh[2] = wos; M.Wm[2] = wos;
        M.bias[0] = bo; M.bias[1] = bo; M.bias[2] = bo;
        M.outf[0] = out; M.outf[1] = out; M.outf[2] = out;
        M.kh = khi; M.km = kmid;
        M.mode[0] = 0; M.mode[1] = 0; M.mode[2] = 0;
        mm_mfma_kernel<<<dim3(32, 32, 1), 64, 0, stream>>>(M);
    }
}